// Round 1
// baseline (485.000 us; speedup 1.0000x reference)
//
#include <hip/hip_runtime.h>

#define N_NODES 50000
#define N_EDGES 800000
#define NFEAT   256
#define NHID    128
#define NCLASS  47

// ---------------- CSR build ----------------

__global__ void init_kernel(float* __restrict__ deg, int* __restrict__ counts,
                            int* __restrict__ cursor, int n) {
    int i = blockIdx.x * blockDim.x + threadIdx.x;
    if (i < n) { deg[i] = 1.0f; counts[i] = 0; cursor[i] = 0; }
}

__global__ void deg_count_kernel(const int* __restrict__ dst, const float* __restrict__ w,
                                 float* __restrict__ deg, int* __restrict__ counts, int E) {
    int e = blockIdx.x * blockDim.x + threadIdx.x;
    if (e >= E) return;
    int d = dst[e];
    atomicAdd(&deg[d], w[e]);
    atomicAdd(&counts[d], 1);
}

__global__ void dinv_kernel(float* __restrict__ deg, int n) {
    int i = blockIdx.x * blockDim.x + threadIdx.x;
    if (i < n) deg[i] = rsqrtf(deg[i]);   // deg >= 1 always (self-loop weight 1)
}

// single-block exclusive scan of counts -> row_ptr (n = 50000, 1024 threads)
__global__ void scan_kernel(const int* __restrict__ counts, int* __restrict__ row_ptr, int n) {
    __shared__ int sums[1024];
    int t = threadIdx.x;
    const int CH = (n + 1023) / 1024;
    int lo = t * CH;
    int hi = lo + CH; if (hi > n) hi = n;
    int s = 0;
    for (int i = lo; i < hi; ++i) s += counts[i];
    sums[t] = s;
    __syncthreads();
    for (int off = 1; off < 1024; off <<= 1) {
        int v = sums[t];
        int add = (t >= off) ? sums[t - off] : 0;
        __syncthreads();
        sums[t] = v + add;
        __syncthreads();
    }
    int run = sums[t] - s;   // exclusive prefix for this chunk
    for (int i = lo; i < hi; ++i) { row_ptr[i] = run; run += counts[i]; }
    if (t == 1023) row_ptr[n] = sums[1023];
}

__global__ void scatter_kernel(const int* __restrict__ src, const int* __restrict__ dst,
                               const float* __restrict__ w, const float* __restrict__ dinv,
                               const int* __restrict__ row_ptr, int* __restrict__ cursor,
                               int* __restrict__ csr_src, float* __restrict__ csr_w, int E) {
    int e = blockIdx.x * blockDim.x + threadIdx.x;
    if (e >= E) return;
    int d = dst[e], s = src[e];
    int p = row_ptr[d] + atomicAdd(&cursor[d], 1);
    csr_src[p] = s;
    csr_w[p] = dinv[s] * w[e] * dinv[d];
}

// ---------------- Layer 1 GEMM: h1 = x @ W1  (50000x256 @ 256x128) ----------------
// block = 128 threads (one per output feature), 8 nodes per block, x-tile in LDS.

#define G1_NB 8
__global__ __launch_bounds__(128) void gemm1_kernel(const float* __restrict__ x,
                                                    const float* __restrict__ W1,
                                                    float* __restrict__ h1) {
    __shared__ float xs[G1_NB][NFEAT];
    int o = threadIdx.x;
    int node0 = blockIdx.x * G1_NB;
    const float4* xv = (const float4*)(x + (size_t)node0 * NFEAT);
    float4* xsv = (float4*)&xs[0][0];
    #pragma unroll
    for (int i = 0; i < G1_NB * NFEAT / 4 / 128; ++i)
        xsv[o + i * 128] = xv[o + i * 128];
    __syncthreads();
    float acc[G1_NB];
    #pragma unroll
    for (int j = 0; j < G1_NB; ++j) acc[j] = 0.f;
    for (int k = 0; k < NFEAT; k += 4) {
        float w0 = W1[(k + 0) * NHID + o];
        float w1 = W1[(k + 1) * NHID + o];
        float w2 = W1[(k + 2) * NHID + o];
        float w3 = W1[(k + 3) * NHID + o];
        #pragma unroll
        for (int j = 0; j < G1_NB; ++j) {
            float4 xj = *(const float4*)&xs[j][k];
            acc[j] = fmaf(xj.x, w0, acc[j]);
            acc[j] = fmaf(xj.y, w1, acc[j]);
            acc[j] = fmaf(xj.z, w2, acc[j]);
            acc[j] = fmaf(xj.w, w3, acc[j]);
        }
    }
    #pragma unroll
    for (int j = 0; j < G1_NB; ++j)
        h1[(size_t)(node0 + j) * NHID + o] = acc[j];
}

// ---------------- Aggregation 1: hagg = relu(A_norm @ h1 + b1) ----------------
// one block (128 threads) per node; thread = feature

__global__ __launch_bounds__(128) void agg1_kernel(const float* __restrict__ h1,
                                                   const int* __restrict__ row_ptr,
                                                   const int* __restrict__ csr_src,
                                                   const float* __restrict__ csr_w,
                                                   const float* __restrict__ dinv,
                                                   const float* __restrict__ b1,
                                                   float* __restrict__ hagg) {
    int i = blockIdx.x;
    int f = threadIdx.x;
    float di = dinv[i];
    float acc = di * di * h1[(size_t)i * NHID + f];   // self-loop term
    int lo = row_ptr[i], hi = row_ptr[i + 1];
    for (int e = lo; e < hi; ++e) {
        int s = csr_src[e];
        acc = fmaf(csr_w[e], h1[(size_t)s * NHID + f], acc);
    }
    acc += b1[f];
    hagg[(size_t)i * NHID + f] = fmaxf(acc, 0.f);
}

// ---------------- Layer 2 GEMM: h2 = hagg @ W2  (50000x128 @ 128x47) ----------------
// W2 staged in LDS; one wave per node, lane = class (47 active)

__global__ __launch_bounds__(256) void gemm2_kernel(const float* __restrict__ hagg,
                                                    const float* __restrict__ W2,
                                                    float* __restrict__ h2, int n) {
    __shared__ float w2s[NHID * NCLASS];
    for (int i = threadIdx.x; i < NHID * NCLASS; i += 256) w2s[i] = W2[i];
    __syncthreads();
    int wave = threadIdx.x >> 6, lane = threadIdx.x & 63;
    int node = blockIdx.x * 4 + wave;
    if (node >= n) return;
    const float* hr = hagg + (size_t)node * NHID;
    float acc = 0.f;
    if (lane < NCLASS) {
        #pragma unroll 4
        for (int k = 0; k < NHID; ++k)
            acc = fmaf(hr[k], w2s[k * NCLASS + lane], acc);
        h2[(size_t)node * NCLASS + lane] = acc;
    }
}

// ---------------- Aggregation 2 + bias + log_softmax -> out ----------------
// one wave (64 threads) per node, lane = class (47 active)

__global__ __launch_bounds__(64) void agg2_kernel(const float* __restrict__ h2,
                                                  const int* __restrict__ row_ptr,
                                                  const int* __restrict__ csr_src,
                                                  const float* __restrict__ csr_w,
                                                  const float* __restrict__ dinv,
                                                  const float* __restrict__ b2,
                                                  float* __restrict__ out) {
    int i = blockIdx.x;
    int c = threadIdx.x;   // 0..63
    float di = dinv[i];
    float acc = 0.f;
    if (c < NCLASS) acc = di * di * h2[(size_t)i * NCLASS + c];
    int lo = row_ptr[i], hi = row_ptr[i + 1];
    for (int e = lo; e < hi; ++e) {
        int s = csr_src[e];
        float w = csr_w[e];
        if (c < NCLASS) acc = fmaf(w, h2[(size_t)s * NCLASS + c], acc);
    }
    float v = (c < NCLASS) ? (acc + b2[c]) : -1e30f;
    float m = v;
    #pragma unroll
    for (int off = 32; off; off >>= 1) m = fmaxf(m, __shfl_xor(m, off));
    float ex = (c < NCLASS) ? __expf(v - m) : 0.f;
    float ssum = ex;
    #pragma unroll
    for (int off = 32; off; off >>= 1) ssum += __shfl_xor(ssum, off);
    if (c < NCLASS) out[(size_t)i * NCLASS + c] = v - m - __logf(ssum);
}

// ---------------- launch ----------------

extern "C" void kernel_launch(void* const* d_in, const int* in_sizes, int n_in,
                              void* d_out, int out_size, void* d_ws, size_t ws_size,
                              hipStream_t stream) {
    const float* x  = (const float*)d_in[0];
    const int*   ei = (const int*)d_in[1];
    const float* ew = (const float*)d_in[2];
    const float* W1 = (const float*)d_in[3];
    const float* b1 = (const float*)d_in[4];
    const float* W2 = (const float*)d_in[5];
    const float* b2 = (const float*)d_in[6];
    float* out = (float*)d_out;

    const int* e_src = ei;
    const int* e_dst = ei + N_EDGES;

    // carve workspace (256B aligned)
    char* p = (char*)d_ws;
    auto carve = [&](size_t bytes) { void* r = (void*)p; p += (bytes + 255) & ~(size_t)255; return r; };
    float* dinv    = (float*)carve(N_NODES * 4);          // deg -> dinv in place
    int*   counts  = (int*)  carve(N_NODES * 4);
    int*   cursor  = (int*)  carve(N_NODES * 4);
    int*   row_ptr = (int*)  carve((N_NODES + 1) * 4);
    int*   csr_src = (int*)  carve(N_EDGES * 4);
    float* csr_w   = (float*)carve(N_EDGES * 4);
    float* h1      = (float*)carve((size_t)N_NODES * NHID * 4);
    float* hagg    = (float*)carve((size_t)N_NODES * NHID * 4);
    float* h2      = (float*)carve((size_t)N_NODES * NCLASS * 4);

    init_kernel<<<(N_NODES + 255) / 256, 256, 0, stream>>>(dinv, counts, cursor, N_NODES);
    deg_count_kernel<<<(N_EDGES + 255) / 256, 256, 0, stream>>>(e_dst, ew, dinv, counts, N_EDGES);
    dinv_kernel<<<(N_NODES + 255) / 256, 256, 0, stream>>>(dinv, N_NODES);
    scan_kernel<<<1, 1024, 0, stream>>>(counts, row_ptr, N_NODES);
    scatter_kernel<<<(N_EDGES + 255) / 256, 256, 0, stream>>>(e_src, e_dst, ew, dinv, row_ptr,
                                                              cursor, csr_src, csr_w, N_EDGES);
    gemm1_kernel<<<N_NODES / G1_NB, 128, 0, stream>>>(x, W1, h1);
    agg1_kernel<<<N_NODES, 128, 0, stream>>>(h1, row_ptr, csr_src, csr_w, dinv, b1, hagg);
    gemm2_kernel<<<(N_NODES + 3) / 4, 256, 0, stream>>>(hagg, W2, h2, N_NODES);
    agg2_kernel<<<N_NODES, 64, 0, stream>>>(h2, row_ptr, csr_src, csr_w, dinv, b2, out);
}

// Round 2
// 476.707 us; speedup vs baseline: 1.0174x; 1.0174x over previous
//
#include <hip/hip_runtime.h>

#define N_NODES 50000
#define N_EDGES 800000
#define NFEAT   256
#define NHID    128
#define NCLASS  47

// ---------------- CSR build ----------------

__global__ void init_kernel(float* __restrict__ deg, int* __restrict__ counts,
                            int* __restrict__ cursor, int n) {
    int i = blockIdx.x * blockDim.x + threadIdx.x;
    if (i < n) { deg[i] = 1.0f; counts[i] = 0; cursor[i] = 0; }
}

__global__ void deg_count_kernel(const int* __restrict__ dst, const float* __restrict__ w,
                                 float* __restrict__ deg, int* __restrict__ counts, int E) {
    int e = blockIdx.x * blockDim.x + threadIdx.x;
    if (e >= E) return;
    int d = dst[e];
    atomicAdd(&deg[d], w[e]);
    atomicAdd(&counts[d], 1);
}

__global__ void dinv_kernel(float* __restrict__ deg, int n) {
    int i = blockIdx.x * blockDim.x + threadIdx.x;
    if (i < n) deg[i] = rsqrtf(deg[i]);   // deg >= 1 always (self-loop weight 1)
}

// single-block exclusive scan of counts -> row_ptr (n = 50000, 1024 threads)
__global__ void scan_kernel(const int* __restrict__ counts, int* __restrict__ row_ptr, int n) {
    __shared__ int sums[1024];
    int t = threadIdx.x;
    const int CH = (n + 1023) / 1024;
    int lo = t * CH;
    int hi = lo + CH; if (hi > n) hi = n;
    int s = 0;
    for (int i = lo; i < hi; ++i) s += counts[i];
    sums[t] = s;
    __syncthreads();
    for (int off = 1; off < 1024; off <<= 1) {
        int v = sums[t];
        int add = (t >= off) ? sums[t - off] : 0;
        __syncthreads();
        sums[t] = v + add;
        __syncthreads();
    }
    int run = sums[t] - s;   // exclusive prefix for this chunk
    for (int i = lo; i < hi; ++i) { row_ptr[i] = run; run += counts[i]; }
    if (t == 1023) row_ptr[n] = sums[1023];
}

// pack (src, weight) into int2 so the edge loop does one dwordx2 load per edge
__global__ void scatter_kernel(const int* __restrict__ src, const int* __restrict__ dst,
                               const float* __restrict__ w, const float* __restrict__ dinv,
                               const int* __restrict__ row_ptr, int* __restrict__ cursor,
                               int2* __restrict__ csr, int E) {
    int e = blockIdx.x * blockDim.x + threadIdx.x;
    if (e >= E) return;
    int d = dst[e], s = src[e];
    int p = row_ptr[d] + atomicAdd(&cursor[d], 1);
    int2 pr;
    pr.x = s;
    pr.y = __float_as_int(dinv[s] * w[e] * dinv[d]);
    csr[p] = pr;
}

// ---------------- Layer 1 GEMM: h1 = x @ W1  (50000x256 @ 256x128) ----------------
// block = 256 threads; 16 nodes per block; thread = (feat-pair o2, node-group g).
// LDS reads are wave-uniform -> broadcast, conflict-free. 8 FMA per ds_read_b128.

#define G1_NB 16
__global__ __launch_bounds__(256) void gemm1_kernel(const float* __restrict__ x,
                                                    const float* __restrict__ W1,
                                                    float* __restrict__ h1) {
    __shared__ float xs[G1_NB][NFEAT];   // 16 KiB
    int tid = threadIdx.x;
    int o2 = tid & 63;           // feature pair -> feats 2*o2, 2*o2+1
    int g  = tid >> 6;           // node group 0..3 -> nodes g*4 .. g*4+3
    int node0 = blockIdx.x * G1_NB;
    const float4* xv = (const float4*)(x + (size_t)node0 * NFEAT);
    float4* xsv = (float4*)&xs[0][0];
    #pragma unroll
    for (int i = 0; i < 4; ++i) xsv[tid + i * 256] = xv[tid + i * 256];
    __syncthreads();
    float2 acc[4] = {};
    for (int k = 0; k < NFEAT; k += 4) {
        float2 w0 = *(const float2*)&W1[(k + 0) * NHID + 2 * o2];
        float2 w1 = *(const float2*)&W1[(k + 1) * NHID + 2 * o2];
        float2 w2 = *(const float2*)&W1[(k + 2) * NHID + 2 * o2];
        float2 w3 = *(const float2*)&W1[(k + 3) * NHID + 2 * o2];
        #pragma unroll
        for (int j = 0; j < 4; ++j) {
            float4 xj = *(const float4*)&xs[g * 4 + j][k];
            acc[j].x = fmaf(xj.x, w0.x, acc[j].x); acc[j].y = fmaf(xj.x, w0.y, acc[j].y);
            acc[j].x = fmaf(xj.y, w1.x, acc[j].x); acc[j].y = fmaf(xj.y, w1.y, acc[j].y);
            acc[j].x = fmaf(xj.z, w2.x, acc[j].x); acc[j].y = fmaf(xj.z, w2.y, acc[j].y);
            acc[j].x = fmaf(xj.w, w3.x, acc[j].x); acc[j].y = fmaf(xj.w, w3.y, acc[j].y);
        }
    }
    #pragma unroll
    for (int j = 0; j < 4; ++j)
        *(float2*)&h1[(size_t)(node0 + g * 4 + j) * NHID + 2 * o2] = acc[j];
}

// ---------------- Aggregation 1: hagg = relu(A_norm @ h1 + b1) ----------------
// one block (128 threads) per node; thread = feature; edge loop unrolled x8 for ILP

__global__ __launch_bounds__(128) void agg1_kernel(const float* __restrict__ h1,
                                                   const int* __restrict__ row_ptr,
                                                   const int2* __restrict__ csr,
                                                   const float* __restrict__ dinv,
                                                   const float* __restrict__ b1,
                                                   float* __restrict__ hagg) {
    int i = blockIdx.x;
    int f = threadIdx.x;
    const float* h1f = h1 + f;
    float di = dinv[i];
    float acc = di * di * h1f[(size_t)i * NHID];   // self-loop
    int lo = row_ptr[i], hi = row_ptr[i + 1];
    int e = lo;
    for (; e + 8 <= hi; e += 8) {
        int2 p0 = csr[e + 0], p1 = csr[e + 1], p2 = csr[e + 2], p3 = csr[e + 3];
        int2 p4 = csr[e + 4], p5 = csr[e + 5], p6 = csr[e + 6], p7 = csr[e + 7];
        float v0 = h1f[(size_t)p0.x * NHID];
        float v1 = h1f[(size_t)p1.x * NHID];
        float v2 = h1f[(size_t)p2.x * NHID];
        float v3 = h1f[(size_t)p3.x * NHID];
        float v4 = h1f[(size_t)p4.x * NHID];
        float v5 = h1f[(size_t)p5.x * NHID];
        float v6 = h1f[(size_t)p6.x * NHID];
        float v7 = h1f[(size_t)p7.x * NHID];
        acc = fmaf(__int_as_float(p0.y), v0, acc);
        acc = fmaf(__int_as_float(p1.y), v1, acc);
        acc = fmaf(__int_as_float(p2.y), v2, acc);
        acc = fmaf(__int_as_float(p3.y), v3, acc);
        acc = fmaf(__int_as_float(p4.y), v4, acc);
        acc = fmaf(__int_as_float(p5.y), v5, acc);
        acc = fmaf(__int_as_float(p6.y), v6, acc);
        acc = fmaf(__int_as_float(p7.y), v7, acc);
    }
    for (; e < hi; ++e) {
        int2 p = csr[e];
        acc = fmaf(__int_as_float(p.y), h1f[(size_t)p.x * NHID], acc);
    }
    acc += b1[f];
    hagg[(size_t)i * NHID + f] = fmaxf(acc, 0.f);
}

// ---------------- Layer 2 GEMM: h2 = hagg @ W2  (50000x128 @ 128x47) ----------------
// W2 staged in LDS; one wave per node, lane = class (47 active)

__global__ __launch_bounds__(256) void gemm2_kernel(const float* __restrict__ hagg,
                                                    const float* __restrict__ W2,
                                                    float* __restrict__ h2, int n) {
    __shared__ float w2s[NHID * NCLASS];
    for (int i = threadIdx.x; i < NHID * NCLASS; i += 256) w2s[i] = W2[i];
    __syncthreads();
    int wave = threadIdx.x >> 6, lane = threadIdx.x & 63;
    int node = blockIdx.x * 4 + wave;
    if (node >= n) return;
    const float* hr = hagg + (size_t)node * NHID;
    float acc = 0.f;
    if (lane < NCLASS) {
        #pragma unroll 4
        for (int k = 0; k < NHID; ++k)
            acc = fmaf(hr[k], w2s[k * NCLASS + lane], acc);
        h2[(size_t)node * NCLASS + lane] = acc;
    }
}

// ---------------- Aggregation 2 + bias + log_softmax -> out ----------------
// block = 256 threads = 4 waves = 4 nodes; lane = class; edge loop unrolled x8

__global__ __launch_bounds__(256) void agg2_kernel(const float* __restrict__ h2,
                                                   const int* __restrict__ row_ptr,
                                                   const int2* __restrict__ csr,
                                                   const float* __restrict__ dinv,
                                                   const float* __restrict__ b2,
                                                   float* __restrict__ out, int n) {
    int wave = threadIdx.x >> 6, c = threadIdx.x & 63;
    int i = blockIdx.x * 4 + wave;
    if (i >= n) return;
    int cc = (c < NCLASS) ? c : 0;           // clamp address; lanes >=47 discarded
    const float* h2c = h2 + cc;
    float di = dinv[i];
    float acc = di * di * h2c[(size_t)i * NCLASS];
    int lo = row_ptr[i], hi = row_ptr[i + 1];
    int e = lo;
    for (; e + 8 <= hi; e += 8) {
        int2 p0 = csr[e + 0], p1 = csr[e + 1], p2 = csr[e + 2], p3 = csr[e + 3];
        int2 p4 = csr[e + 4], p5 = csr[e + 5], p6 = csr[e + 6], p7 = csr[e + 7];
        float v0 = h2c[(size_t)p0.x * NCLASS];
        float v1 = h2c[(size_t)p1.x * NCLASS];
        float v2 = h2c[(size_t)p2.x * NCLASS];
        float v3 = h2c[(size_t)p3.x * NCLASS];
        float v4 = h2c[(size_t)p4.x * NCLASS];
        float v5 = h2c[(size_t)p5.x * NCLASS];
        float v6 = h2c[(size_t)p6.x * NCLASS];
        float v7 = h2c[(size_t)p7.x * NCLASS];
        acc = fmaf(__int_as_float(p0.y), v0, acc);
        acc = fmaf(__int_as_float(p1.y), v1, acc);
        acc = fmaf(__int_as_float(p2.y), v2, acc);
        acc = fmaf(__int_as_float(p3.y), v3, acc);
        acc = fmaf(__int_as_float(p4.y), v4, acc);
        acc = fmaf(__int_as_float(p5.y), v5, acc);
        acc = fmaf(__int_as_float(p6.y), v6, acc);
        acc = fmaf(__int_as_float(p7.y), v7, acc);
    }
    for (; e < hi; ++e) {
        int2 p = csr[e];
        acc = fmaf(__int_as_float(p.y), h2c[(size_t)p.x * NCLASS], acc);
    }
    float v = (c < NCLASS) ? (acc + b2[c]) : -1e30f;
    float m = v;
    #pragma unroll
    for (int off = 32; off; off >>= 1) m = fmaxf(m, __shfl_xor(m, off));
    float ex = (c < NCLASS) ? __expf(v - m) : 0.f;
    float ssum = ex;
    #pragma unroll
    for (int off = 32; off; off >>= 1) ssum += __shfl_xor(ssum, off);
    if (c < NCLASS) out[(size_t)i * NCLASS + c] = v - m - __logf(ssum);
}

// ---------------- launch ----------------

extern "C" void kernel_launch(void* const* d_in, const int* in_sizes, int n_in,
                              void* d_out, int out_size, void* d_ws, size_t ws_size,
                              hipStream_t stream) {
    const float* x  = (const float*)d_in[0];
    const int*   ei = (const int*)d_in[1];
    const float* ew = (const float*)d_in[2];
    const float* W1 = (const float*)d_in[3];
    const float* b1 = (const float*)d_in[4];
    const float* W2 = (const float*)d_in[5];
    const float* b2 = (const float*)d_in[6];
    float* out = (float*)d_out;

    const int* e_src = ei;
    const int* e_dst = ei + N_EDGES;

    char* p = (char*)d_ws;
    auto carve = [&](size_t bytes) { void* r = (void*)p; p += (bytes + 255) & ~(size_t)255; return r; };
    float* dinv    = (float*)carve(N_NODES * 4);          // deg -> dinv in place
    int*   counts  = (int*)  carve(N_NODES * 4);
    int*   cursor  = (int*)  carve(N_NODES * 4);
    int*   row_ptr = (int*)  carve((N_NODES + 1) * 4);
    int2*  csr     = (int2*) carve((size_t)N_EDGES * 8);
    float* h1      = (float*)carve((size_t)N_NODES * NHID * 4);
    float* hagg    = (float*)carve((size_t)N_NODES * NHID * 4);
    float* h2      = (float*)carve((size_t)N_NODES * NCLASS * 4);

    init_kernel<<<(N_NODES + 255) / 256, 256, 0, stream>>>(dinv, counts, cursor, N_NODES);
    deg_count_kernel<<<(N_EDGES + 255) / 256, 256, 0, stream>>>(e_dst, ew, dinv, counts, N_EDGES);
    dinv_kernel<<<(N_NODES + 255) / 256, 256, 0, stream>>>(dinv, N_NODES);
    scan_kernel<<<1, 1024, 0, stream>>>(counts, row_ptr, N_NODES);
    scatter_kernel<<<(N_EDGES + 255) / 256, 256, 0, stream>>>(e_src, e_dst, ew, dinv, row_ptr,
                                                              cursor, csr, N_EDGES);
    gemm1_kernel<<<N_NODES / G1_NB, 256, 0, stream>>>(x, W1, h1);
    agg1_kernel<<<N_NODES, 128, 0, stream>>>(h1, row_ptr, csr, dinv, b1, hagg);
    gemm2_kernel<<<(N_NODES + 3) / 4, 256, 0, stream>>>(hagg, W2, h2, N_NODES);
    agg2_kernel<<<(N_NODES + 3) / 4, 256, 0, stream>>>(h2, row_ptr, csr, dinv, b2, out, N_NODES);
}

// Round 3
// 349.235 us; speedup vs baseline: 1.3887x; 1.3650x over previous
//
#include <hip/hip_runtime.h>

#define N_NODES 50000
#define N_EDGES 800000
#define NFEAT   256
#define NHID    128
#define NCLASS  47

typedef __attribute__((ext_vector_type(8))) short short8v;
typedef __attribute__((ext_vector_type(4))) float f32x4;

__device__ __forceinline__ ushort f2bf(float f) {
    unsigned u = __float_as_uint(f);
    unsigned r = (u + 0x7FFF + ((u >> 16) & 1)) >> 16;   // round-to-nearest-even
    return (ushort)r;
}

// ---------------- CSR build ----------------

__global__ void init_kernel(float* __restrict__ deg, int* __restrict__ counts,
                            int* __restrict__ cursor, int n) {
    int i = blockIdx.x * blockDim.x + threadIdx.x;
    if (i < n) { deg[i] = 1.0f; counts[i] = 0; cursor[i] = 0; }
}

__global__ void deg_count_kernel(const int* __restrict__ dst, const float* __restrict__ w,
                                 float* __restrict__ deg, int* __restrict__ counts, int E) {
    int e = blockIdx.x * blockDim.x + threadIdx.x;
    if (e >= E) return;
    int d = dst[e];
    atomicAdd(&deg[d], w[e]);
    atomicAdd(&counts[d], 1);
}

__global__ void dinv_kernel(float* __restrict__ deg, int n) {
    int i = blockIdx.x * blockDim.x + threadIdx.x;
    if (i < n) deg[i] = rsqrtf(deg[i]);   // deg >= 1 always (self-loop weight 1)
}

__global__ void scan_kernel(const int* __restrict__ counts, int* __restrict__ row_ptr, int n) {
    __shared__ int sums[1024];
    int t = threadIdx.x;
    const int CH = (n + 1023) / 1024;
    int lo = t * CH;
    int hi = lo + CH; if (hi > n) hi = n;
    int s = 0;
    for (int i = lo; i < hi; ++i) s += counts[i];
    sums[t] = s;
    __syncthreads();
    for (int off = 1; off < 1024; off <<= 1) {
        int v = sums[t];
        int add = (t >= off) ? sums[t - off] : 0;
        __syncthreads();
        sums[t] = v + add;
        __syncthreads();
    }
    int run = sums[t] - s;
    for (int i = lo; i < hi; ++i) { row_ptr[i] = run; run += counts[i]; }
    if (t == 1023) row_ptr[n] = sums[1023];
}

__global__ void scatter_kernel(const int* __restrict__ src, const int* __restrict__ dst,
                               const float* __restrict__ w, const float* __restrict__ dinv,
                               const int* __restrict__ row_ptr, int* __restrict__ cursor,
                               int2* __restrict__ csr, int E) {
    int e = blockIdx.x * blockDim.x + threadIdx.x;
    if (e >= E) return;
    int d = dst[e], s = src[e];
    int p = row_ptr[d] + atomicAdd(&cursor[d], 1);
    int2 pr;
    pr.x = s;
    pr.y = __float_as_int(dinv[s] * w[e] * dinv[d]);
    csr[p] = pr;
}

// ---------------- Layer 1 GEMM (MFMA bf16): h1 = x @ W1 ----------------
// block 256 thr = 4 waves (2Mx2N); tile 64 nodes x 128 feats; K-steps of 64.
// LDS rows padded to 72 bf16 (144B = 36 dw, 36%32=4 -> only free 2-way conflicts).

__global__ __launch_bounds__(256) void gemm1_kernel(const float* __restrict__ x,
                                                    const float* __restrict__ W1,
                                                    float* __restrict__ h1) {
    __shared__ __align__(16) ushort xs[64][72];    // A tile: 64 nodes x 64 k
    __shared__ __align__(16) ushort ws[128][72];   // B^T tile: 128 cols x 64 k
    int tid = threadIdx.x;
    int node0 = blockIdx.x * 64;
    int wave = tid >> 6, l = tid & 63;
    int fr = l & 15, fq = l >> 4;
    int r0 = (wave >> 1) * 32;     // wave row base (2 waves in M)
    int c0 = (wave & 1) * 64;      // wave col base (2 waves in N)

    f32x4 acc[2][4] = {};

    for (int kk0 = 0; kk0 < NFEAT; kk0 += 64) {
        // stage x tile: thread -> row=tid>>2, 16 consecutive k
        {
            int row = tid >> 2, q = tid & 3;
            int srow = node0 + row; if (srow >= N_NODES) srow = N_NODES - 1;
            const float4* src = (const float4*)(x + (size_t)srow * NFEAT + kk0 + q * 16);
            ushort tmp[16];
            #pragma unroll
            for (int i = 0; i < 4; ++i) {
                float4 v = src[i];
                tmp[i * 4 + 0] = f2bf(v.x); tmp[i * 4 + 1] = f2bf(v.y);
                tmp[i * 4 + 2] = f2bf(v.z); tmp[i * 4 + 3] = f2bf(v.w);
            }
            #pragma unroll
            for (int i = 0; i < 2; ++i)
                *(short8v*)&xs[row][q * 16 + i * 8] = *(short8v*)&tmp[i * 8];
        }
        // stage W1^T tile: read W1[k][c0..c0+3] coalesced, scatter-write transposed
        {
            int c4 = (tid & 31) * 4;
            int kb = tid >> 5;
            #pragma unroll
            for (int r = 0; r < 8; ++r) {
                int k = kk0 + kb + r * 8;
                float4 v = *(const float4*)(W1 + (size_t)k * NHID + c4);
                ws[c4 + 0][k - kk0] = f2bf(v.x);
                ws[c4 + 1][k - kk0] = f2bf(v.y);
                ws[c4 + 2][k - kk0] = f2bf(v.z);
                ws[c4 + 3][k - kk0] = f2bf(v.w);
            }
        }
        __syncthreads();
        short8v a[2][2], b[4][2];
        #pragma unroll
        for (int m = 0; m < 2; ++m)
            #pragma unroll
            for (int kf = 0; kf < 2; ++kf)
                a[m][kf] = *(const short8v*)&xs[r0 + m * 16 + fr][kf * 32 + fq * 8];
        #pragma unroll
        for (int n = 0; n < 4; ++n)
            #pragma unroll
            for (int kf = 0; kf < 2; ++kf)
                b[n][kf] = *(const short8v*)&ws[c0 + n * 16 + fr][kf * 32 + fq * 8];
        #pragma unroll
        for (int m = 0; m < 2; ++m)
            #pragma unroll
            for (int n = 0; n < 4; ++n)
                #pragma unroll
                for (int kf = 0; kf < 2; ++kf)
                    acc[m][n] = __builtin_amdgcn_mfma_f32_16x16x32_bf16(
                        a[m][kf], b[n][kf], acc[m][n], 0, 0, 0);
        __syncthreads();
    }
    #pragma unroll
    for (int m = 0; m < 2; ++m) {
        #pragma unroll
        for (int n = 0; n < 4; ++n) {
            #pragma unroll
            for (int j = 0; j < 4; ++j) {
                int gr = node0 + r0 + m * 16 + fq * 4 + j;
                if (gr < N_NODES)
                    h1[(size_t)gr * NHID + c0 + n * 16 + fr] = acc[m][n][j];
            }
        }
    }
}

// ---------------- Aggregation 1: haggb = bf16(relu(A_norm @ h1 + b1)) ----------------

__global__ __launch_bounds__(128) void agg1_kernel(const float* __restrict__ h1,
                                                   const int* __restrict__ row_ptr,
                                                   const int2* __restrict__ csr,
                                                   const float* __restrict__ dinv,
                                                   const float* __restrict__ b1,
                                                   ushort* __restrict__ haggb) {
    int i = blockIdx.x;
    int f = threadIdx.x;
    const float* h1f = h1 + f;
    float di = dinv[i];
    float acc = di * di * h1f[(size_t)i * NHID];   // self-loop
    int lo = row_ptr[i], hi = row_ptr[i + 1];
    int e = lo;
    for (; e + 8 <= hi; e += 8) {
        int2 p0 = csr[e + 0], p1 = csr[e + 1], p2 = csr[e + 2], p3 = csr[e + 3];
        int2 p4 = csr[e + 4], p5 = csr[e + 5], p6 = csr[e + 6], p7 = csr[e + 7];
        float v0 = h1f[(size_t)p0.x * NHID];
        float v1 = h1f[(size_t)p1.x * NHID];
        float v2 = h1f[(size_t)p2.x * NHID];
        float v3 = h1f[(size_t)p3.x * NHID];
        float v4 = h1f[(size_t)p4.x * NHID];
        float v5 = h1f[(size_t)p5.x * NHID];
        float v6 = h1f[(size_t)p6.x * NHID];
        float v7 = h1f[(size_t)p7.x * NHID];
        acc = fmaf(__int_as_float(p0.y), v0, acc);
        acc = fmaf(__int_as_float(p1.y), v1, acc);
        acc = fmaf(__int_as_float(p2.y), v2, acc);
        acc = fmaf(__int_as_float(p3.y), v3, acc);
        acc = fmaf(__int_as_float(p4.y), v4, acc);
        acc = fmaf(__int_as_float(p5.y), v5, acc);
        acc = fmaf(__int_as_float(p6.y), v6, acc);
        acc = fmaf(__int_as_float(p7.y), v7, acc);
    }
    for (; e < hi; ++e) {
        int2 p = csr[e];
        acc = fmaf(__int_as_float(p.y), h1f[(size_t)p.x * NHID], acc);
    }
    acc += b1[f];
    haggb[(size_t)i * NHID + f] = f2bf(fmaxf(acc, 0.f));
}

// ---------------- Layer 2 GEMM (MFMA bf16): h2 = hagg @ W2 ----------------
// block 256 thr = 4 waves (1 wave = 16 rows); tile 64 nodes x 48 cols (47 valid); K=128.

__global__ __launch_bounds__(256) void gemm2_kernel(const ushort* __restrict__ haggb,
                                                    const float* __restrict__ W2,
                                                    float* __restrict__ h2) {
    __shared__ __align__(16) ushort ha[64][136];    // 64 nodes x 128 k
    __shared__ __align__(16) ushort wt[48][136];    // W2^T: 48 cols x 128 k
    int tid = threadIdx.x;
    int node0 = blockIdx.x * 64;
    // stage hagg tile (bf16, coalesced 16B loads)
    {
        int row = tid >> 2, q = tid & 3;
        int srow = node0 + row; if (srow >= N_NODES) srow = N_NODES - 1;
        const short8v* src = (const short8v*)(haggb + (size_t)srow * NHID + q * 32);
        #pragma unroll
        for (int i = 0; i < 4; ++i)
            *(short8v*)&ha[row][q * 32 + i * 8] = src[i];
    }
    // stage W2^T (convert f32 -> bf16; col 47 zero-padded)
    {
        #pragma unroll
        for (int r = 0; r < 24; ++r) {
            int idx = r * 256 + tid;
            int c = idx >> 7, k = idx & 127;
            float v = (c < NCLASS) ? W2[(size_t)k * NCLASS + c] : 0.f;
            wt[c][k] = f2bf(v);
        }
    }
    __syncthreads();
    int wave = tid >> 6, l = tid & 63;
    int fr = l & 15, fq = l >> 4;
    int r0 = wave * 16;
    short8v a[4], b[3][4];
    #pragma unroll
    for (int kf = 0; kf < 4; ++kf)
        a[kf] = *(const short8v*)&ha[r0 + fr][kf * 32 + fq * 8];
    #pragma unroll
    for (int n = 0; n < 3; ++n)
        #pragma unroll
        for (int kf = 0; kf < 4; ++kf)
            b[n][kf] = *(const short8v*)&wt[n * 16 + fr][kf * 32 + fq * 8];
    f32x4 acc[3] = {};
    #pragma unroll
    for (int n = 0; n < 3; ++n)
        #pragma unroll
        for (int kf = 0; kf < 4; ++kf)
            acc[n] = __builtin_amdgcn_mfma_f32_16x16x32_bf16(a[kf], b[n][kf], acc[n], 0, 0, 0);
    #pragma unroll
    for (int n = 0; n < 3; ++n) {
        #pragma unroll
        for (int j = 0; j < 4; ++j) {
            int gr = node0 + r0 + fq * 4 + j;
            int col = n * 16 + fr;
            if (gr < N_NODES && col < NCLASS)
                h2[(size_t)gr * NCLASS + col] = acc[n][j];
        }
    }
}

// ---------------- Aggregation 2 + bias + log_softmax -> out ----------------

__global__ __launch_bounds__(256) void agg2_kernel(const float* __restrict__ h2,
                                                   const int* __restrict__ row_ptr,
                                                   const int2* __restrict__ csr,
                                                   const float* __restrict__ dinv,
                                                   const float* __restrict__ b2,
                                                   float* __restrict__ out, int n) {
    int wave = threadIdx.x >> 6, c = threadIdx.x & 63;
    int i = blockIdx.x * 4 + wave;
    if (i >= n) return;
    int cc = (c < NCLASS) ? c : 0;
    const float* h2c = h2 + cc;
    float di = dinv[i];
    float acc = di * di * h2c[(size_t)i * NCLASS];
    int lo = row_ptr[i], hi = row_ptr[i + 1];
    int e = lo;
    for (; e + 8 <= hi; e += 8) {
        int2 p0 = csr[e + 0], p1 = csr[e + 1], p2 = csr[e + 2], p3 = csr[e + 3];
        int2 p4 = csr[e + 4], p5 = csr[e + 5], p6 = csr[e + 6], p7 = csr[e + 7];
        float v0 = h2c[(size_t)p0.x * NCLASS];
        float v1 = h2c[(size_t)p1.x * NCLASS];
        float v2 = h2c[(size_t)p2.x * NCLASS];
        float v3 = h2c[(size_t)p3.x * NCLASS];
        float v4 = h2c[(size_t)p4.x * NCLASS];
        float v5 = h2c[(size_t)p5.x * NCLASS];
        float v6 = h2c[(size_t)p6.x * NCLASS];
        float v7 = h2c[(size_t)p7.x * NCLASS];
        acc = fmaf(__int_as_float(p0.y), v0, acc);
        acc = fmaf(__int_as_float(p1.y), v1, acc);
        acc = fmaf(__int_as_float(p2.y), v2, acc);
        acc = fmaf(__int_as_float(p3.y), v3, acc);
        acc = fmaf(__int_as_float(p4.y), v4, acc);
        acc = fmaf(__int_as_float(p5.y), v5, acc);
        acc = fmaf(__int_as_float(p6.y), v6, acc);
        acc = fmaf(__int_as_float(p7.y), v7, acc);
    }
    for (; e < hi; ++e) {
        int2 p = csr[e];
        acc = fmaf(__int_as_float(p.y), h2c[(size_t)p.x * NCLASS], acc);
    }
    float v = (c < NCLASS) ? (acc + b2[c]) : -1e30f;
    float m = v;
    #pragma unroll
    for (int off = 32; off; off >>= 1) m = fmaxf(m, __shfl_xor(m, off));
    float ex = (c < NCLASS) ? __expf(v - m) : 0.f;
    float ssum = ex;
    #pragma unroll
    for (int off = 32; off; off >>= 1) ssum += __shfl_xor(ssum, off);
    if (c < NCLASS) out[(size_t)i * NCLASS + c] = v - m - __logf(ssum);
}

// ---------------- launch ----------------

extern "C" void kernel_launch(void* const* d_in, const int* in_sizes, int n_in,
                              void* d_out, int out_size, void* d_ws, size_t ws_size,
                              hipStream_t stream) {
    const float* x  = (const float*)d_in[0];
    const int*   ei = (const int*)d_in[1];
    const float* ew = (const float*)d_in[2];
    const float* W1 = (const float*)d_in[3];
    const float* b1 = (const float*)d_in[4];
    const float* W2 = (const float*)d_in[5];
    const float* b2 = (const float*)d_in[6];
    float* out = (float*)d_out;

    const int* e_src = ei;
    const int* e_dst = ei + N_EDGES;

    char* p = (char*)d_ws;
    auto carve = [&](size_t bytes) { void* r = (void*)p; p += (bytes + 255) & ~(size_t)255; return r; };
    float*  dinv    = (float*) carve(N_NODES * 4);
    int*    counts  = (int*)   carve(N_NODES * 4);
    int*    cursor  = (int*)   carve(N_NODES * 4);
    int*    row_ptr = (int*)   carve((N_NODES + 1) * 4);
    int2*   csr     = (int2*)  carve((size_t)N_EDGES * 8);
    float*  h1      = (float*) carve((size_t)N_NODES * NHID * 4);
    ushort* haggb   = (ushort*)carve((size_t)N_NODES * NHID * 2);
    float*  h2      = (float*) carve((size_t)N_NODES * NCLASS * 4);

    init_kernel<<<(N_NODES + 255) / 256, 256, 0, stream>>>(dinv, counts, cursor, N_NODES);
    deg_count_kernel<<<(N_EDGES + 255) / 256, 256, 0, stream>>>(e_dst, ew, dinv, counts, N_EDGES);
    dinv_kernel<<<(N_NODES + 255) / 256, 256, 0, stream>>>(dinv, N_NODES);
    scan_kernel<<<1, 1024, 0, stream>>>(counts, row_ptr, N_NODES);
    scatter_kernel<<<(N_EDGES + 255) / 256, 256, 0, stream>>>(e_src, e_dst, ew, dinv, row_ptr,
                                                              cursor, csr, N_EDGES);
    gemm1_kernel<<<(N_NODES + 63) / 64, 256, 0, stream>>>(x, W1, h1);
    agg1_kernel<<<N_NODES, 128, 0, stream>>>(h1, row_ptr, csr, dinv, b1, haggb);
    gemm2_kernel<<<(N_NODES + 63) / 64, 256, 0, stream>>>(haggb, W2, h2);
    agg2_kernel<<<(N_NODES + 3) / 4, 256, 0, stream>>>(h2, row_ptr, csr, dinv, b2, out, N_NODES);
}

// Round 4
// 268.104 us; speedup vs baseline: 1.8090x; 1.3026x over previous
//
#include <hip/hip_runtime.h>

#define N_NODES 50000
#define N_EDGES 800000
#define NFEAT   256
#define NHID    128
#define NCLASS  47
#define H2P     48    // padded h2 row (bf16)

typedef __attribute__((ext_vector_type(8))) short short8v;
typedef __attribute__((ext_vector_type(4))) float f32x4;

__device__ __forceinline__ ushort f2bf(float f) {
    unsigned u = __float_as_uint(f);
    unsigned r = (u + 0x7FFF + ((u >> 16) & 1)) >> 16;   // round-to-nearest-even
    return (ushort)r;
}
__device__ __forceinline__ float bf2f(ushort b) {
    return __uint_as_float(((unsigned)b) << 16);
}

// ---------------- CSR build ----------------

__global__ void init_kernel(float* __restrict__ deg, int* __restrict__ counts,
                            int* __restrict__ cursor, int* __restrict__ total, int n) {
    int i = blockIdx.x * blockDim.x + threadIdx.x;
    if (i < n) { deg[i] = 1.0f; counts[i] = 0; cursor[i] = 0; }
    if (i == 0) *total = 0;
}

__global__ void deg_count_kernel(const int* __restrict__ dst, const float* __restrict__ w,
                                 float* __restrict__ deg, int* __restrict__ counts, int E) {
    int e = blockIdx.x * blockDim.x + threadIdx.x;
    if (e >= E) return;
    int d = dst[e];
    atomicAdd(&deg[d], w[e]);
    atomicAdd(&counts[d], 1);
}

__global__ void dinv_kernel(float* __restrict__ deg, int n) {
    int i = blockIdx.x * blockDim.x + threadIdx.x;
    if (i < n) deg[i] = rsqrtf(deg[i]);   // deg >= 1 always (self-loop weight 1)
}

// segment allocator: block-local scan + one atomicAdd per block for the base.
// Segments are disjoint; ordering is irrelevant for correctness (scatter already
// uses per-node cursor atomics, so within-segment order is arbitrary anyway).
__global__ __launch_bounds__(256) void segalloc_kernel(const int* __restrict__ counts,
                                                       int* __restrict__ row_start,
                                                       int* __restrict__ total, int n) {
    __shared__ int s[256];
    __shared__ int base_s;
    int t = threadIdx.x;
    int i = blockIdx.x * 256 + t;
    int v = (i < n) ? counts[i] : 0;
    s[t] = v;
    __syncthreads();
    #pragma unroll
    for (int off = 1; off < 256; off <<= 1) {
        int x = s[t];
        if (t >= off) x += s[t - off];
        __syncthreads();
        s[t] = x;
        __syncthreads();
    }
    if (t == 255) base_s = atomicAdd(total, s[255]);
    __syncthreads();
    if (i < n) row_start[i] = base_s + s[t] - v;
}

__global__ void scatter_kernel(const int* __restrict__ src, const int* __restrict__ dst,
                               const float* __restrict__ w, const float* __restrict__ dinv,
                               const int* __restrict__ row_start, int* __restrict__ cursor,
                               int2* __restrict__ csr, int E) {
    int e = blockIdx.x * blockDim.x + threadIdx.x;
    if (e >= E) return;
    int d = dst[e], s = src[e];
    int p = row_start[d] + atomicAdd(&cursor[d], 1);
    int2 pr;
    pr.x = s;
    pr.y = __float_as_int(dinv[s] * w[e] * dinv[d]);
    csr[p] = pr;
}

// ---------------- Layer 1 GEMM (MFMA bf16): h1b = bf16(x @ W1) ----------------

__global__ __launch_bounds__(256) void gemm1_kernel(const float* __restrict__ x,
                                                    const float* __restrict__ W1,
                                                    ushort* __restrict__ h1b) {
    __shared__ __align__(16) ushort xs[64][72];
    __shared__ __align__(16) ushort ws[128][72];
    int tid = threadIdx.x;
    int node0 = blockIdx.x * 64;
    int wave = tid >> 6, l = tid & 63;
    int fr = l & 15, fq = l >> 4;
    int r0 = (wave >> 1) * 32;
    int c0 = (wave & 1) * 64;

    f32x4 acc[2][4] = {};

    for (int kk0 = 0; kk0 < NFEAT; kk0 += 64) {
        {
            int row = tid >> 2, q = tid & 3;
            int srow = node0 + row; if (srow >= N_NODES) srow = N_NODES - 1;
            const float4* src = (const float4*)(x + (size_t)srow * NFEAT + kk0 + q * 16);
            ushort tmp[16];
            #pragma unroll
            for (int i = 0; i < 4; ++i) {
                float4 v = src[i];
                tmp[i * 4 + 0] = f2bf(v.x); tmp[i * 4 + 1] = f2bf(v.y);
                tmp[i * 4 + 2] = f2bf(v.z); tmp[i * 4 + 3] = f2bf(v.w);
            }
            #pragma unroll
            for (int i = 0; i < 2; ++i)
                *(short8v*)&xs[row][q * 16 + i * 8] = *(short8v*)&tmp[i * 8];
        }
        {
            int c4 = (tid & 31) * 4;
            int kb = tid >> 5;
            #pragma unroll
            for (int r = 0; r < 8; ++r) {
                int k = kk0 + kb + r * 8;
                float4 v = *(const float4*)(W1 + (size_t)k * NHID + c4);
                ws[c4 + 0][k - kk0] = f2bf(v.x);
                ws[c4 + 1][k - kk0] = f2bf(v.y);
                ws[c4 + 2][k - kk0] = f2bf(v.z);
                ws[c4 + 3][k - kk0] = f2bf(v.w);
            }
        }
        __syncthreads();
        short8v a[2][2], b[4][2];
        #pragma unroll
        for (int m = 0; m < 2; ++m)
            #pragma unroll
            for (int kf = 0; kf < 2; ++kf)
                a[m][kf] = *(const short8v*)&xs[r0 + m * 16 + fr][kf * 32 + fq * 8];
        #pragma unroll
        for (int n = 0; n < 4; ++n)
            #pragma unroll
            for (int kf = 0; kf < 2; ++kf)
                b[n][kf] = *(const short8v*)&ws[c0 + n * 16 + fr][kf * 32 + fq * 8];
        #pragma unroll
        for (int m = 0; m < 2; ++m)
            #pragma unroll
            for (int n = 0; n < 4; ++n)
                #pragma unroll
                for (int kf = 0; kf < 2; ++kf)
                    acc[m][n] = __builtin_amdgcn_mfma_f32_16x16x32_bf16(
                        a[m][kf], b[n][kf], acc[m][n], 0, 0, 0);
        __syncthreads();
    }
    #pragma unroll
    for (int m = 0; m < 2; ++m) {
        #pragma unroll
        for (int n = 0; n < 4; ++n) {
            #pragma unroll
            for (int j = 0; j < 4; ++j) {
                int gr = node0 + r0 + m * 16 + fq * 4 + j;
                if (gr < N_NODES)
                    h1b[(size_t)gr * NHID + c0 + n * 16 + fr] = f2bf(acc[m][n][j]);
            }
        }
    }
}

// ---------------- Aggregation 1: haggb = bf16(relu(A_norm @ h1 + b1)) ----------------

__global__ __launch_bounds__(128) void agg1_kernel(const ushort* __restrict__ h1b,
                                                   const int* __restrict__ row_start,
                                                   const int* __restrict__ counts,
                                                   const int2* __restrict__ csr,
                                                   const float* __restrict__ dinv,
                                                   const float* __restrict__ b1,
                                                   ushort* __restrict__ haggb) {
    int i = blockIdx.x;
    int f = threadIdx.x;
    const ushort* h1f = h1b + f;
    float di = dinv[i];
    float acc = di * di * bf2f(h1f[(size_t)i * NHID]);   // self-loop
    int lo = row_start[i], hi = lo + counts[i];
    int e = lo;
    for (; e + 8 <= hi; e += 8) {
        int2 p0 = csr[e + 0], p1 = csr[e + 1], p2 = csr[e + 2], p3 = csr[e + 3];
        int2 p4 = csr[e + 4], p5 = csr[e + 5], p6 = csr[e + 6], p7 = csr[e + 7];
        float v0 = bf2f(h1f[(size_t)p0.x * NHID]);
        float v1 = bf2f(h1f[(size_t)p1.x * NHID]);
        float v2 = bf2f(h1f[(size_t)p2.x * NHID]);
        float v3 = bf2f(h1f[(size_t)p3.x * NHID]);
        float v4 = bf2f(h1f[(size_t)p4.x * NHID]);
        float v5 = bf2f(h1f[(size_t)p5.x * NHID]);
        float v6 = bf2f(h1f[(size_t)p6.x * NHID]);
        float v7 = bf2f(h1f[(size_t)p7.x * NHID]);
        acc = fmaf(__int_as_float(p0.y), v0, acc);
        acc = fmaf(__int_as_float(p1.y), v1, acc);
        acc = fmaf(__int_as_float(p2.y), v2, acc);
        acc = fmaf(__int_as_float(p3.y), v3, acc);
        acc = fmaf(__int_as_float(p4.y), v4, acc);
        acc = fmaf(__int_as_float(p5.y), v5, acc);
        acc = fmaf(__int_as_float(p6.y), v6, acc);
        acc = fmaf(__int_as_float(p7.y), v7, acc);
    }
    for (; e < hi; ++e) {
        int2 p = csr[e];
        acc = fmaf(__int_as_float(p.y), bf2f(h1f[(size_t)p.x * NHID]), acc);
    }
    acc += b1[f];
    haggb[(size_t)i * NHID + f] = f2bf(fmaxf(acc, 0.f));
}

// ---------------- Layer 2 GEMM (MFMA bf16): h2b = bf16(hagg @ W2), rows padded to 48 ----------------

__global__ __launch_bounds__(256) void gemm2_kernel(const ushort* __restrict__ haggb,
                                                    const float* __restrict__ W2,
                                                    ushort* __restrict__ h2b) {
    __shared__ __align__(16) ushort ha[64][136];
    __shared__ __align__(16) ushort wt[48][136];
    int tid = threadIdx.x;
    int node0 = blockIdx.x * 64;
    {
        int row = tid >> 2, q = tid & 3;
        int srow = node0 + row; if (srow >= N_NODES) srow = N_NODES - 1;
        const short8v* src = (const short8v*)(haggb + (size_t)srow * NHID + q * 32);
        #pragma unroll
        for (int i = 0; i < 4; ++i)
            *(short8v*)&ha[row][q * 32 + i * 8] = src[i];
    }
    {
        #pragma unroll
        for (int r = 0; r < 24; ++r) {
            int idx = r * 256 + tid;
            int c = idx >> 7, k = idx & 127;
            float v = (c < NCLASS) ? W2[(size_t)k * NCLASS + c] : 0.f;
            wt[c][k] = f2bf(v);
        }
    }
    __syncthreads();
    int wave = tid >> 6, l = tid & 63;
    int fr = l & 15, fq = l >> 4;
    int r0 = wave * 16;
    short8v a[4], b[3][4];
    #pragma unroll
    for (int kf = 0; kf < 4; ++kf)
        a[kf] = *(const short8v*)&ha[r0 + fr][kf * 32 + fq * 8];
    #pragma unroll
    for (int n = 0; n < 3; ++n)
        #pragma unroll
        for (int kf = 0; kf < 4; ++kf)
            b[n][kf] = *(const short8v*)&wt[n * 16 + fr][kf * 32 + fq * 8];
    f32x4 acc[3] = {};
    #pragma unroll
    for (int n = 0; n < 3; ++n)
        #pragma unroll
        for (int kf = 0; kf < 4; ++kf)
            acc[n] = __builtin_amdgcn_mfma_f32_16x16x32_bf16(a[kf], b[n][kf], acc[n], 0, 0, 0);
    #pragma unroll
    for (int n = 0; n < 3; ++n) {
        #pragma unroll
        for (int j = 0; j < 4; ++j) {
            int gr = node0 + r0 + fq * 4 + j;
            int col = n * 16 + fr;
            if (gr < N_NODES && col < H2P)
                h2b[(size_t)gr * H2P + col] = (col < NCLASS) ? f2bf(acc[n][j]) : 0;
        }
    }
}

// ---------------- Aggregation 2 + bias + log_softmax -> out ----------------

__global__ __launch_bounds__(256) void agg2_kernel(const ushort* __restrict__ h2b,
                                                   const int* __restrict__ row_start,
                                                   const int* __restrict__ counts,
                                                   const int2* __restrict__ csr,
                                                   const float* __restrict__ dinv,
                                                   const float* __restrict__ b2,
                                                   float* __restrict__ out, int n) {
    int wave = threadIdx.x >> 6, c = threadIdx.x & 63;
    int i = blockIdx.x * 4 + wave;
    if (i >= n) return;
    int cc = (c < NCLASS) ? c : 0;
    const ushort* h2c = h2b + cc;
    float di = dinv[i];
    float acc = di * di * bf2f(h2c[(size_t)i * H2P]);
    int lo = row_start[i], hi = lo + counts[i];
    int e = lo;
    for (; e + 8 <= hi; e += 8) {
        int2 p0 = csr[e + 0], p1 = csr[e + 1], p2 = csr[e + 2], p3 = csr[e + 3];
        int2 p4 = csr[e + 4], p5 = csr[e + 5], p6 = csr[e + 6], p7 = csr[e + 7];
        float v0 = bf2f(h2c[(size_t)p0.x * H2P]);
        float v1 = bf2f(h2c[(size_t)p1.x * H2P]);
        float v2 = bf2f(h2c[(size_t)p2.x * H2P]);
        float v3 = bf2f(h2c[(size_t)p3.x * H2P]);
        float v4 = bf2f(h2c[(size_t)p4.x * H2P]);
        float v5 = bf2f(h2c[(size_t)p5.x * H2P]);
        float v6 = bf2f(h2c[(size_t)p6.x * H2P]);
        float v7 = bf2f(h2c[(size_t)p7.x * H2P]);
        acc = fmaf(__int_as_float(p0.y), v0, acc);
        acc = fmaf(__int_as_float(p1.y), v1, acc);
        acc = fmaf(__int_as_float(p2.y), v2, acc);
        acc = fmaf(__int_as_float(p3.y), v3, acc);
        acc = fmaf(__int_as_float(p4.y), v4, acc);
        acc = fmaf(__int_as_float(p5.y), v5, acc);
        acc = fmaf(__int_as_float(p6.y), v6, acc);
        acc = fmaf(__int_as_float(p7.y), v7, acc);
    }
    for (; e < hi; ++e) {
        int2 p = csr[e];
        acc = fmaf(__int_as_float(p.y), bf2f(h2c[(size_t)p.x * H2P]), acc);
    }
    float v = (c < NCLASS) ? (acc + b2[c]) : -1e30f;
    float m = v;
    #pragma unroll
    for (int off = 32; off; off >>= 1) m = fmaxf(m, __shfl_xor(m, off));
    float ex = (c < NCLASS) ? __expf(v - m) : 0.f;
    float ssum = ex;
    #pragma unroll
    for (int off = 32; off; off >>= 1) ssum += __shfl_xor(ssum, off);
    if (c < NCLASS) out[(size_t)i * NCLASS + c] = v - m - __logf(ssum);
}

// ---------------- launch ----------------

extern "C" void kernel_launch(void* const* d_in, const int* in_sizes, int n_in,
                              void* d_out, int out_size, void* d_ws, size_t ws_size,
                              hipStream_t stream) {
    const float* x  = (const float*)d_in[0];
    const int*   ei = (const int*)d_in[1];
    const float* ew = (const float*)d_in[2];
    const float* W1 = (const float*)d_in[3];
    const float* b1 = (const float*)d_in[4];
    const float* W2 = (const float*)d_in[5];
    const float* b2 = (const float*)d_in[6];
    float* out = (float*)d_out;

    const int* e_src = ei;
    const int* e_dst = ei + N_EDGES;

    char* p = (char*)d_ws;
    auto carve = [&](size_t bytes) { void* r = (void*)p; p += (bytes + 255) & ~(size_t)255; return r; };
    float*  dinv      = (float*) carve(N_NODES * 4);
    int*    counts    = (int*)   carve(N_NODES * 4);
    int*    cursor    = (int*)   carve(N_NODES * 4);
    int*    row_start = (int*)   carve(N_NODES * 4);
    int*    total     = (int*)   carve(4);
    int2*   csr       = (int2*)  carve((size_t)N_EDGES * 8);
    ushort* h1b       = (ushort*)carve((size_t)N_NODES * NHID * 2);
    ushort* haggb     = (ushort*)carve((size_t)N_NODES * NHID * 2);
    ushort* h2b       = (ushort*)carve((size_t)N_NODES * H2P * 2);

    init_kernel<<<(N_NODES + 255) / 256, 256, 0, stream>>>(dinv, counts, cursor, total, N_NODES);
    deg_count_kernel<<<(N_EDGES + 255) / 256, 256, 0, stream>>>(e_dst, ew, dinv, counts, N_EDGES);
    dinv_kernel<<<(N_NODES + 255) / 256, 256, 0, stream>>>(dinv, N_NODES);
    segalloc_kernel<<<(N_NODES + 255) / 256, 256, 0, stream>>>(counts, row_start, total, N_NODES);
    scatter_kernel<<<(N_EDGES + 255) / 256, 256, 0, stream>>>(e_src, e_dst, ew, dinv, row_start,
                                                              cursor, csr, N_EDGES);
    gemm1_kernel<<<(N_NODES + 63) / 64, 256, 0, stream>>>(x, W1, h1b);
    agg1_kernel<<<N_NODES, 128, 0, stream>>>(h1b, row_start, counts, csr, dinv, b1, haggb);
    gemm2_kernel<<<(N_NODES + 63) / 64, 256, 0, stream>>>(haggb, W2, h2b);
    agg2_kernel<<<(N_NODES + 3) / 4, 256, 0, stream>>>(h2b, row_start, counts, csr, dinv, b2, out, N_NODES);
}

// Round 5
// 198.625 us; speedup vs baseline: 2.4418x; 1.3498x over previous
//
#include <hip/hip_runtime.h>

#define N_NODES 50000
#define N_EDGES 800000
#define NFEAT   256
#define NHID    128
#define NCLASS  47
#define H2P     48    // padded h2 row (bf16)
#define CSR_MAX (N_EDGES + 7 * N_NODES)   // every segment padded to multiple of 8

typedef __attribute__((ext_vector_type(8))) short short8v;
typedef __attribute__((ext_vector_type(4))) float f32x4;

__device__ __forceinline__ ushort f2bf(float f) {
    unsigned u = __float_as_uint(f);
    unsigned r = (u + 0x7FFF + ((u >> 16) & 1)) >> 16;   // round-to-nearest-even
    return (ushort)r;
}
__device__ __forceinline__ float bf2f(ushort b) {
    return __uint_as_float(((unsigned)b) << 16);
}

// ---------------- CSR build ----------------
// packed[d]: high 24 bits = edge count, low 40 bits = sum(w) in 2^-20 fixed point.
// One 64-bit atomic per edge; the returned old count doubles as the CSR slot index.

__global__ void init_kernel(unsigned long long* __restrict__ packed,
                            int* __restrict__ total, int n) {
    int i = blockIdx.x * blockDim.x + threadIdx.x;
    if (i < n) packed[i] = 0ull;
    if (i == 0) *total = 0;
}

__global__ void csr_zero_kernel(int2* __restrict__ csr) {
    int i = blockIdx.x * blockDim.x + threadIdx.x;
    if (i < CSR_MAX) csr[i] = make_int2(0, 0);   // src=0, w=+0.0f (pad entries)
}

__global__ void degcnt_kernel(const int* __restrict__ dst, const float* __restrict__ w,
                              unsigned long long* __restrict__ packed,
                              int* __restrict__ pos, int E) {
    int e = blockIdx.x * blockDim.x + threadIdx.x;
    if (e >= E) return;
    int d = dst[e];
    unsigned fx = __float2uint_rn(w[e] * 1048576.0f);
    unsigned long long old = atomicAdd(&packed[d], (1ull << 40) | (unsigned long long)fx);
    pos[e] = (int)(old >> 40);
}

__global__ void dinv_kernel(const unsigned long long* __restrict__ packed,
                            float* __restrict__ dinv, int* __restrict__ counts, int n) {
    int i = blockIdx.x * blockDim.x + threadIdx.x;
    if (i >= n) return;
    unsigned long long v = packed[i];
    counts[i] = (int)(v >> 40);
    float deg = 1.0f + (float)(v & 0xFFFFFFFFFFull) * (1.0f / 1048576.0f);
    dinv[i] = rsqrtf(deg);
}

// segment allocator: block-local scan + one atomicAdd per block for the base.
// Segment sizes padded to multiple of 8 so the aggregators have no serial tail.
__global__ __launch_bounds__(256) void segalloc_kernel(const int* __restrict__ counts,
                                                       int* __restrict__ row_start,
                                                       int* __restrict__ total, int n) {
    __shared__ int s[256];
    __shared__ int base_s;
    int t = threadIdx.x;
    int i = blockIdx.x * 256 + t;
    int v = (i < n) ? ((counts[i] + 7) & ~7) : 0;
    s[t] = v;
    __syncthreads();
    #pragma unroll
    for (int off = 1; off < 256; off <<= 1) {
        int x = s[t];
        if (t >= off) x += s[t - off];
        __syncthreads();
        s[t] = x;
        __syncthreads();
    }
    if (t == 255) base_s = atomicAdd(total, s[255]);
    __syncthreads();
    if (i < n) row_start[i] = base_s + s[t] - v;
}

// atomic-free scatter: slot index was allocated by degcnt's returned count
__global__ void scatter_kernel(const int* __restrict__ src, const int* __restrict__ dst,
                               const float* __restrict__ w, const int* __restrict__ pos,
                               const float* __restrict__ dinv,
                               const int* __restrict__ row_start,
                               int2* __restrict__ csr, int E) {
    int e = blockIdx.x * blockDim.x + threadIdx.x;
    if (e >= E) return;
    int d = dst[e], s = src[e];
    int p = row_start[d] + pos[e];
    int2 pr;
    pr.x = s;
    pr.y = __float_as_int(dinv[s] * w[e] * dinv[d]);
    csr[p] = pr;
}

// ---------------- Layer 1 GEMM (MFMA bf16): h1b = bf16(x @ W1) ----------------

__global__ __launch_bounds__(256) void gemm1_kernel(const float* __restrict__ x,
                                                    const float* __restrict__ W1,
                                                    ushort* __restrict__ h1b) {
    __shared__ __align__(16) ushort xs[64][72];
    __shared__ __align__(16) ushort ws[128][72];
    int tid = threadIdx.x;
    int node0 = blockIdx.x * 64;
    int wave = tid >> 6, l = tid & 63;
    int fr = l & 15, fq = l >> 4;
    int r0 = (wave >> 1) * 32;
    int c0 = (wave & 1) * 64;

    f32x4 acc[2][4] = {};

    for (int kk0 = 0; kk0 < NFEAT; kk0 += 64) {
        {
            int row = tid >> 2, q = tid & 3;
            int srow = node0 + row; if (srow >= N_NODES) srow = N_NODES - 1;
            const float4* src = (const float4*)(x + (size_t)srow * NFEAT + kk0 + q * 16);
            ushort tmp[16];
            #pragma unroll
            for (int i = 0; i < 4; ++i) {
                float4 v = src[i];
                tmp[i * 4 + 0] = f2bf(v.x); tmp[i * 4 + 1] = f2bf(v.y);
                tmp[i * 4 + 2] = f2bf(v.z); tmp[i * 4 + 3] = f2bf(v.w);
            }
            #pragma unroll
            for (int i = 0; i < 2; ++i)
                *(short8v*)&xs[row][q * 16 + i * 8] = *(short8v*)&tmp[i * 8];
        }
        {
            int c4 = (tid & 31) * 4;
            int kb = tid >> 5;
            #pragma unroll
            for (int r = 0; r < 8; ++r) {
                int k = kk0 + kb + r * 8;
                float4 v = *(const float4*)(W1 + (size_t)k * NHID + c4);
                ws[c4 + 0][k - kk0] = f2bf(v.x);
                ws[c4 + 1][k - kk0] = f2bf(v.y);
                ws[c4 + 2][k - kk0] = f2bf(v.z);
                ws[c4 + 3][k - kk0] = f2bf(v.w);
            }
        }
        __syncthreads();
        short8v a[2][2], b[4][2];
        #pragma unroll
        for (int m = 0; m < 2; ++m)
            #pragma unroll
            for (int kf = 0; kf < 2; ++kf)
                a[m][kf] = *(const short8v*)&xs[r0 + m * 16 + fr][kf * 32 + fq * 8];
        #pragma unroll
        for (int n = 0; n < 4; ++n)
            #pragma unroll
            for (int kf = 0; kf < 2; ++kf)
                b[n][kf] = *(const short8v*)&ws[c0 + n * 16 + fr][kf * 32 + fq * 8];
        #pragma unroll
        for (int m = 0; m < 2; ++m)
            #pragma unroll
            for (int n = 0; n < 4; ++n)
                #pragma unroll
                for (int kf = 0; kf < 2; ++kf)
                    acc[m][n] = __builtin_amdgcn_mfma_f32_16x16x32_bf16(
                        a[m][kf], b[n][kf], acc[m][n], 0, 0, 0);
        __syncthreads();
    }
    #pragma unroll
    for (int m = 0; m < 2; ++m) {
        #pragma unroll
        for (int n = 0; n < 4; ++n) {
            #pragma unroll
            for (int j = 0; j < 4; ++j) {
                int gr = node0 + r0 + m * 16 + fq * 4 + j;
                if (gr < N_NODES)
                    h1b[(size_t)gr * NHID + c0 + n * 16 + fr] = f2bf(acc[m][n][j]);
            }
        }
    }
}

// ---------------- Aggregation 1: haggb = bf16(relu(A_norm @ h1 + b1)) ----------------
// segments are multiples of 8 -> fully pipelined 8-deep gathers, no serial tail

__global__ __launch_bounds__(128) void agg1_kernel(const ushort* __restrict__ h1b,
                                                   const int* __restrict__ row_start,
                                                   const int* __restrict__ counts,
                                                   const int2* __restrict__ csr,
                                                   const float* __restrict__ dinv,
                                                   const float* __restrict__ b1,
                                                   ushort* __restrict__ haggb) {
    int i = blockIdx.x;
    int f = threadIdx.x;
    const ushort* h1f = h1b + f;
    float di = dinv[i];
    float acc = di * di * bf2f(h1f[(size_t)i * NHID]);   // self-loop
    int lo = row_start[i], hi = lo + ((counts[i] + 7) & ~7);
    for (int e = lo; e < hi; e += 8) {
        int2 p0 = csr[e + 0], p1 = csr[e + 1], p2 = csr[e + 2], p3 = csr[e + 3];
        int2 p4 = csr[e + 4], p5 = csr[e + 5], p6 = csr[e + 6], p7 = csr[e + 7];
        float v0 = bf2f(h1f[(size_t)p0.x * NHID]);
        float v1 = bf2f(h1f[(size_t)p1.x * NHID]);
        float v2 = bf2f(h1f[(size_t)p2.x * NHID]);
        float v3 = bf2f(h1f[(size_t)p3.x * NHID]);
        float v4 = bf2f(h1f[(size_t)p4.x * NHID]);
        float v5 = bf2f(h1f[(size_t)p5.x * NHID]);
        float v6 = bf2f(h1f[(size_t)p6.x * NHID]);
        float v7 = bf2f(h1f[(size_t)p7.x * NHID]);
        acc = fmaf(__int_as_float(p0.y), v0, acc);
        acc = fmaf(__int_as_float(p1.y), v1, acc);
        acc = fmaf(__int_as_float(p2.y), v2, acc);
        acc = fmaf(__int_as_float(p3.y), v3, acc);
        acc = fmaf(__int_as_float(p4.y), v4, acc);
        acc = fmaf(__int_as_float(p5.y), v5, acc);
        acc = fmaf(__int_as_float(p6.y), v6, acc);
        acc = fmaf(__int_as_float(p7.y), v7, acc);
    }
    acc += b1[f];
    haggb[(size_t)i * NHID + f] = f2bf(fmaxf(acc, 0.f));
}

// ---------------- Layer 2 GEMM (MFMA bf16): h2b = bf16(hagg @ W2), rows padded to 48 ----------------

__global__ __launch_bounds__(256) void gemm2_kernel(const ushort* __restrict__ haggb,
                                                    const float* __restrict__ W2,
                                                    ushort* __restrict__ h2b) {
    __shared__ __align__(16) ushort ha[64][136];
    __shared__ __align__(16) ushort wt[48][136];
    int tid = threadIdx.x;
    int node0 = blockIdx.x * 64;
    {
        int row = tid >> 2, q = tid & 3;
        int srow = node0 + row; if (srow >= N_NODES) srow = N_NODES - 1;
        const short8v* src = (const short8v*)(haggb + (size_t)srow * NHID + q * 32);
        #pragma unroll
        for (int i = 0; i < 4; ++i)
            *(short8v*)&ha[row][q * 32 + i * 8] = src[i];
    }
    {
        #pragma unroll
        for (int r = 0; r < 24; ++r) {
            int idx = r * 256 + tid;
            int c = idx >> 7, k = idx & 127;
            float v = (c < NCLASS) ? W2[(size_t)k * NCLASS + c] : 0.f;
            wt[c][k] = f2bf(v);
        }
    }
    __syncthreads();
    int wave = tid >> 6, l = tid & 63;
    int fr = l & 15, fq = l >> 4;
    int r0 = wave * 16;
    short8v a[4], b[3][4];
    #pragma unroll
    for (int kf = 0; kf < 4; ++kf)
        a[kf] = *(const short8v*)&ha[r0 + fr][kf * 32 + fq * 8];
    #pragma unroll
    for (int n = 0; n < 3; ++n)
        #pragma unroll
        for (int kf = 0; kf < 4; ++kf)
            b[n][kf] = *(const short8v*)&wt[n * 16 + fr][kf * 32 + fq * 8];
    f32x4 acc[3] = {};
    #pragma unroll
    for (int n = 0; n < 3; ++n)
        #pragma unroll
        for (int kf = 0; kf < 4; ++kf)
            acc[n] = __builtin_amdgcn_mfma_f32_16x16x32_bf16(a[kf], b[n][kf], acc[n], 0, 0, 0);
    #pragma unroll
    for (int n = 0; n < 3; ++n) {
        #pragma unroll
        for (int j = 0; j < 4; ++j) {
            int gr = node0 + r0 + fq * 4 + j;
            int col = n * 16 + fr;
            if (gr < N_NODES && col < H2P)
                h2b[(size_t)gr * H2P + col] = (col < NCLASS) ? f2bf(acc[n][j]) : 0;
        }
    }
}

// ---------------- Aggregation 2 + bias + log_softmax -> out ----------------

__global__ __launch_bounds__(256) void agg2_kernel(const ushort* __restrict__ h2b,
                                                   const int* __restrict__ row_start,
                                                   const int* __restrict__ counts,
                                                   const int2* __restrict__ csr,
                                                   const float* __restrict__ dinv,
                                                   const float* __restrict__ b2,
                                                   float* __restrict__ out, int n) {
    int wave = threadIdx.x >> 6, c = threadIdx.x & 63;
    int i = blockIdx.x * 4 + wave;
    if (i >= n) return;
    int cc = (c < NCLASS) ? c : 0;
    const ushort* h2c = h2b + cc;
    float di = dinv[i];
    float acc = di * di * bf2f(h2c[(size_t)i * H2P]);
    int lo = row_start[i], hi = lo + ((counts[i] + 7) & ~7);
    for (int e = lo; e < hi; e += 8) {
        int2 p0 = csr[e + 0], p1 = csr[e + 1], p2 = csr[e + 2], p3 = csr[e + 3];
        int2 p4 = csr[e + 4], p5 = csr[e + 5], p6 = csr[e + 6], p7 = csr[e + 7];
        float v0 = bf2f(h2c[(size_t)p0.x * H2P]);
        float v1 = bf2f(h2c[(size_t)p1.x * H2P]);
        float v2 = bf2f(h2c[(size_t)p2.x * H2P]);
        float v3 = bf2f(h2c[(size_t)p3.x * H2P]);
        float v4 = bf2f(h2c[(size_t)p4.x * H2P]);
        float v5 = bf2f(h2c[(size_t)p5.x * H2P]);
        float v6 = bf2f(h2c[(size_t)p6.x * H2P]);
        float v7 = bf2f(h2c[(size_t)p7.x * H2P]);
        acc = fmaf(__int_as_float(p0.y), v0, acc);
        acc = fmaf(__int_as_float(p1.y), v1, acc);
        acc = fmaf(__int_as_float(p2.y), v2, acc);
        acc = fmaf(__int_as_float(p3.y), v3, acc);
        acc = fmaf(__int_as_float(p4.y), v4, acc);
        acc = fmaf(__int_as_float(p5.y), v5, acc);
        acc = fmaf(__int_as_float(p6.y), v6, acc);
        acc = fmaf(__int_as_float(p7.y), v7, acc);
    }
    float v = (c < NCLASS) ? (acc + b2[c]) : -1e30f;
    float m = v;
    #pragma unroll
    for (int off = 32; off; off >>= 1) m = fmaxf(m, __shfl_xor(m, off));
    float ex = (c < NCLASS) ? __expf(v - m) : 0.f;
    float ssum = ex;
    #pragma unroll
    for (int off = 32; off; off >>= 1) ssum += __shfl_xor(ssum, off);
    if (c < NCLASS) out[(size_t)i * NCLASS + c] = v - m - __logf(ssum);
}

// ---------------- launch ----------------

extern "C" void kernel_launch(void* const* d_in, const int* in_sizes, int n_in,
                              void* d_out, int out_size, void* d_ws, size_t ws_size,
                              hipStream_t stream) {
    const float* x  = (const float*)d_in[0];
    const int*   ei = (const int*)d_in[1];
    const float* ew = (const float*)d_in[2];
    const float* W1 = (const float*)d_in[3];
    const float* b1 = (const float*)d_in[4];
    const float* W2 = (const float*)d_in[5];
    const float* b2 = (const float*)d_in[6];
    float* out = (float*)d_out;

    const int* e_src = ei;
    const int* e_dst = ei + N_EDGES;

    char* p = (char*)d_ws;
    auto carve = [&](size_t bytes) { void* r = (void*)p; p += (bytes + 255) & ~(size_t)255; return r; };
    unsigned long long* packed = (unsigned long long*)carve(N_NODES * 8);
    float*  dinv      = (float*) carve(N_NODES * 4);
    int*    counts    = (int*)   carve(N_NODES * 4);
    int*    row_start = (int*)   carve(N_NODES * 4);
    int*    total     = (int*)   carve(4);
    int*    pos       = (int*)   carve((size_t)N_EDGES * 4);
    int2*   csr       = (int2*)  carve((size_t)CSR_MAX * 8);
    ushort* h1b       = (ushort*)carve((size_t)N_NODES * NHID * 2);
    ushort* haggb     = (ushort*)carve((size_t)N_NODES * NHID * 2);
    ushort* h2b       = (ushort*)carve((size_t)N_NODES * H2P * 2);

    init_kernel<<<(N_NODES + 255) / 256, 256, 0, stream>>>(packed, total, N_NODES);
    csr_zero_kernel<<<(CSR_MAX + 255) / 256, 256, 0, stream>>>(csr);
    degcnt_kernel<<<(N_EDGES + 255) / 256, 256, 0, stream>>>(e_dst, ew, packed, pos, N_EDGES);
    dinv_kernel<<<(N_NODES + 255) / 256, 256, 0, stream>>>(packed, dinv, counts, N_NODES);
    segalloc_kernel<<<(N_NODES + 255) / 256, 256, 0, stream>>>(counts, row_start, total, N_NODES);
    scatter_kernel<<<(N_EDGES + 255) / 256, 256, 0, stream>>>(e_src, e_dst, ew, pos, dinv,
                                                              row_start, csr, N_EDGES);
    gemm1_kernel<<<(N_NODES + 63) / 64, 256, 0, stream>>>(x, W1, h1b);
    agg1_kernel<<<N_NODES, 128, 0, stream>>>(h1b, row_start, counts, csr, dinv, b1, haggb);
    gemm2_kernel<<<(N_NODES + 63) / 64, 256, 0, stream>>>(haggb, W2, h2b);
    agg2_kernel<<<(N_NODES + 3) / 4, 256, 0, stream>>>(h2b, row_start, counts, csr, dinv, b2, out, N_NODES);
}

// Round 6
// 186.155 us; speedup vs baseline: 2.6053x; 1.0670x over previous
//
#include <hip/hip_runtime.h>

#define N_NODES 50000
#define N_EDGES 800000
#define NFEAT   256
#define NHID    128
#define NCLASS  47
#define H2P     48    // padded h2 row (bf16)
#define CSR_MAX (N_EDGES + 7 * N_NODES)   // every segment padded to multiple of 8

typedef __attribute__((ext_vector_type(8))) short short8v;
typedef __attribute__((ext_vector_type(4))) float f32x4;

__device__ __forceinline__ ushort f2bf(float f) {
    unsigned u = __float_as_uint(f);
    unsigned r = (u + 0x7FFF + ((u >> 16) & 1)) >> 16;   // round-to-nearest-even
    return (ushort)r;
}
__device__ __forceinline__ float bf2f(ushort b) {
    return __uint_as_float(((unsigned)b) << 16);
}
__device__ __forceinline__ float blo(unsigned u) { return __uint_as_float(u << 16); }
__device__ __forceinline__ float bhi(unsigned u) { return __uint_as_float(u & 0xFFFF0000u); }

// ---------------- CSR build ----------------
// packed[d]: high 24 bits = edge count, low 40 bits = sum(w) in 2^-20 fixed point.
// One 64-bit atomic per edge; the returned old count doubles as the CSR slot index.

__global__ void zero_init_kernel(unsigned long long* __restrict__ packed,
                                 int2* __restrict__ csr, int* __restrict__ total) {
    int i = blockIdx.x * blockDim.x + threadIdx.x;
    if (i < CSR_MAX) csr[i] = make_int2(0, 0);   // src=0, w=+0.0f (pad entries)
    if (i < N_NODES) packed[i] = 0ull;
    if (i == 0) *total = 0;
}

__global__ void degcnt_kernel(const int* __restrict__ dst, const float* __restrict__ w,
                              unsigned long long* __restrict__ packed,
                              int* __restrict__ pos, int E) {
    int e = blockIdx.x * blockDim.x + threadIdx.x;
    if (e >= E) return;
    int d = dst[e];
    unsigned fx = __float2uint_rn(w[e] * 1048576.0f);
    unsigned long long old = atomicAdd(&packed[d], (1ull << 40) | (unsigned long long)fx);
    pos[e] = (int)(old >> 40);
}

// segment allocator + dinv: block-local scan + one atomicAdd per block for the base.
// Segment sizes padded to multiple of 8 so the aggregators have no serial tail.
__global__ __launch_bounds__(256) void segalloc_kernel(const unsigned long long* __restrict__ packed,
                                                       int* __restrict__ counts,
                                                       float* __restrict__ dinv,
                                                       int* __restrict__ row_start,
                                                       int* __restrict__ total, int n) {
    __shared__ int s[256];
    __shared__ int base_s;
    int t = threadIdx.x;
    int i = blockIdx.x * 256 + t;
    int v = 0;
    if (i < n) {
        unsigned long long pk = packed[i];
        int cnt = (int)(pk >> 40);
        counts[i] = cnt;
        float deg = 1.0f + (float)(pk & 0xFFFFFFFFFFull) * (1.0f / 1048576.0f);
        dinv[i] = rsqrtf(deg);
        v = (cnt + 7) & ~7;
    }
    s[t] = v;
    __syncthreads();
    #pragma unroll
    for (int off = 1; off < 256; off <<= 1) {
        int x = s[t];
        if (t >= off) x += s[t - off];
        __syncthreads();
        s[t] = x;
        __syncthreads();
    }
    if (t == 255) base_s = atomicAdd(total, s[255]);
    __syncthreads();
    if (i < n) row_start[i] = base_s + s[t] - v;
}

// atomic-free scatter: slot index was allocated by degcnt's returned count
__global__ void scatter_kernel(const int* __restrict__ src, const int* __restrict__ dst,
                               const float* __restrict__ w, const int* __restrict__ pos,
                               const float* __restrict__ dinv,
                               const int* __restrict__ row_start,
                               int2* __restrict__ csr, int E) {
    int e = blockIdx.x * blockDim.x + threadIdx.x;
    if (e >= E) return;
    int d = dst[e], s = src[e];
    int p = row_start[d] + pos[e];
    int2 pr;
    pr.x = s;
    pr.y = __float_as_int(dinv[s] * w[e] * dinv[d]);
    csr[p] = pr;
}

// ---------------- Layer 1 GEMM (MFMA bf16): h1b = bf16(x @ W1) ----------------

__global__ __launch_bounds__(256) void gemm1_kernel(const float* __restrict__ x,
                                                    const float* __restrict__ W1,
                                                    ushort* __restrict__ h1b) {
    __shared__ __align__(16) ushort xs[64][72];
    __shared__ __align__(16) ushort ws[128][72];
    int tid = threadIdx.x;
    int node0 = blockIdx.x * 64;
    int wave = tid >> 6, l = tid & 63;
    int fr = l & 15, fq = l >> 4;
    int r0 = (wave >> 1) * 32;
    int c0 = (wave & 1) * 64;

    f32x4 acc[2][4] = {};

    for (int kk0 = 0; kk0 < NFEAT; kk0 += 64) {
        {
            int row = tid >> 2, q = tid & 3;
            int srow = node0 + row; if (srow >= N_NODES) srow = N_NODES - 1;
            const float4* src = (const float4*)(x + (size_t)srow * NFEAT + kk0 + q * 16);
            ushort tmp[16];
            #pragma unroll
            for (int i = 0; i < 4; ++i) {
                float4 v = src[i];
                tmp[i * 4 + 0] = f2bf(v.x); tmp[i * 4 + 1] = f2bf(v.y);
                tmp[i * 4 + 2] = f2bf(v.z); tmp[i * 4 + 3] = f2bf(v.w);
            }
            #pragma unroll
            for (int i = 0; i < 2; ++i)
                *(short8v*)&xs[row][q * 16 + i * 8] = *(short8v*)&tmp[i * 8];
        }
        {
            int c4 = (tid & 31) * 4;
            int kb = tid >> 5;
            #pragma unroll
            for (int r = 0; r < 8; ++r) {
                int k = kk0 + kb + r * 8;
                float4 v = *(const float4*)(W1 + (size_t)k * NHID + c4);
                ws[c4 + 0][k - kk0] = f2bf(v.x);
                ws[c4 + 1][k - kk0] = f2bf(v.y);
                ws[c4 + 2][k - kk0] = f2bf(v.z);
                ws[c4 + 3][k - kk0] = f2bf(v.w);
            }
        }
        __syncthreads();
        short8v a[2][2], b[4][2];
        #pragma unroll
        for (int m = 0; m < 2; ++m)
            #pragma unroll
            for (int kf = 0; kf < 2; ++kf)
                a[m][kf] = *(const short8v*)&xs[r0 + m * 16 + fr][kf * 32 + fq * 8];
        #pragma unroll
        for (int n = 0; n < 4; ++n)
            #pragma unroll
            for (int kf = 0; kf < 2; ++kf)
                b[n][kf] = *(const short8v*)&ws[c0 + n * 16 + fr][kf * 32 + fq * 8];
        #pragma unroll
        for (int m = 0; m < 2; ++m)
            #pragma unroll
            for (int n = 0; n < 4; ++n)
                #pragma unroll
                for (int kf = 0; kf < 2; ++kf)
                    acc[m][n] = __builtin_amdgcn_mfma_f32_16x16x32_bf16(
                        a[m][kf], b[n][kf], acc[m][n], 0, 0, 0);
        __syncthreads();
    }
    #pragma unroll
    for (int m = 0; m < 2; ++m) {
        #pragma unroll
        for (int n = 0; n < 4; ++n) {
            #pragma unroll
            for (int j = 0; j < 4; ++j) {
                int gr = node0 + r0 + m * 16 + fq * 4 + j;
                if (gr < N_NODES)
                    h1b[(size_t)gr * NHID + c0 + n * 16 + fr] = f2bf(acc[m][n][j]);
            }
        }
    }
}

// ---------------- Aggregation 1: haggb = bf16(relu(A_norm @ h1 + b1)) ----------------
// one WAVE per node; lane = (half h, quarter q). Each lane gathers 8B (4 feats);
// the two 32-lane halves process 2 edges per instruction; 8 edges per iteration.

__global__ __launch_bounds__(256) void agg1_kernel(const ushort* __restrict__ h1b,
                                                   const int* __restrict__ row_start,
                                                   const int* __restrict__ counts,
                                                   const int2* __restrict__ csr,
                                                   const float* __restrict__ dinv,
                                                   const float* __restrict__ b1,
                                                   ushort* __restrict__ haggb) {
    int wv = threadIdx.x >> 6;
    int i = blockIdx.x * 4 + wv;
    int l = threadIdx.x & 63;
    int h = l >> 5, q = l & 31;
    const ushort* rowp = h1b + 4 * q;    // this lane's 4-feature slice

    float di = dinv[i];
    float sc = (h == 0) ? di * di : 0.f;
    uint2 sv = *(const uint2*)(rowp + (size_t)i * NHID);
    float4 acc;
    acc.x = sc * blo(sv.x); acc.y = sc * bhi(sv.x);
    acc.z = sc * blo(sv.y); acc.w = sc * bhi(sv.y);

    int lo = row_start[i], hi = lo + ((counts[i] + 7) & ~7);
    for (int e = lo; e < hi; e += 8) {
        int2 pA = csr[e + 0 + h];
        int2 pB = csr[e + 2 + h];
        int2 pC = csr[e + 4 + h];
        int2 pD = csr[e + 6 + h];
        uint2 vA = *(const uint2*)(rowp + (size_t)pA.x * NHID);
        uint2 vB = *(const uint2*)(rowp + (size_t)pB.x * NHID);
        uint2 vC = *(const uint2*)(rowp + (size_t)pC.x * NHID);
        uint2 vD = *(const uint2*)(rowp + (size_t)pD.x * NHID);
        float wA = __int_as_float(pA.y), wB = __int_as_float(pB.y);
        float wC = __int_as_float(pC.y), wD = __int_as_float(pD.y);
        acc.x = fmaf(wA, blo(vA.x), acc.x); acc.y = fmaf(wA, bhi(vA.x), acc.y);
        acc.z = fmaf(wA, blo(vA.y), acc.z); acc.w = fmaf(wA, bhi(vA.y), acc.w);
        acc.x = fmaf(wB, blo(vB.x), acc.x); acc.y = fmaf(wB, bhi(vB.x), acc.y);
        acc.z = fmaf(wB, blo(vB.y), acc.z); acc.w = fmaf(wB, bhi(vB.y), acc.w);
        acc.x = fmaf(wC, blo(vC.x), acc.x); acc.y = fmaf(wC, bhi(vC.x), acc.y);
        acc.z = fmaf(wC, blo(vC.y), acc.z); acc.w = fmaf(wC, bhi(vC.y), acc.w);
        acc.x = fmaf(wD, blo(vD.x), acc.x); acc.y = fmaf(wD, bhi(vD.x), acc.y);
        acc.z = fmaf(wD, blo(vD.y), acc.z); acc.w = fmaf(wD, bhi(vD.y), acc.w);
    }
    // combine the two halves
    acc.x += __shfl_xor(acc.x, 32);
    acc.y += __shfl_xor(acc.y, 32);
    acc.z += __shfl_xor(acc.z, 32);
    acc.w += __shfl_xor(acc.w, 32);
    if (h == 0) {
        float4 bb = *(const float4*)(b1 + 4 * q);
        acc.x = fmaxf(acc.x + bb.x, 0.f);
        acc.y = fmaxf(acc.y + bb.y, 0.f);
        acc.z = fmaxf(acc.z + bb.z, 0.f);
        acc.w = fmaxf(acc.w + bb.w, 0.f);
        uint2 o;
        o.x = (unsigned)f2bf(acc.x) | ((unsigned)f2bf(acc.y) << 16);
        o.y = (unsigned)f2bf(acc.z) | ((unsigned)f2bf(acc.w) << 16);
        *(uint2*)(haggb + (size_t)i * NHID + 4 * q) = o;
    }
}

// ---------------- Layer 2 GEMM (MFMA bf16): h2b = bf16(hagg @ W2), rows padded to 48 ----------------

__global__ __launch_bounds__(256) void gemm2_kernel(const ushort* __restrict__ haggb,
                                                    const float* __restrict__ W2,
                                                    ushort* __restrict__ h2b) {
    __shared__ __align__(16) ushort ha[64][136];
    __shared__ __align__(16) ushort wt[48][136];
    int tid = threadIdx.x;
    int node0 = blockIdx.x * 64;
    {
        int row = tid >> 2, q = tid & 3;
        int srow = node0 + row; if (srow >= N_NODES) srow = N_NODES - 1;
        const short8v* src = (const short8v*)(haggb + (size_t)srow * NHID + q * 32);
        #pragma unroll
        for (int i = 0; i < 4; ++i)
            *(short8v*)&ha[row][q * 32 + i * 8] = src[i];
    }
    {
        #pragma unroll
        for (int r = 0; r < 24; ++r) {
            int idx = r * 256 + tid;
            int c = idx >> 7, k = idx & 127;
            float v = (c < NCLASS) ? W2[(size_t)k * NCLASS + c] : 0.f;
            wt[c][k] = f2bf(v);
        }
    }
    __syncthreads();
    int wave = tid >> 6, l = tid & 63;
    int fr = l & 15, fq = l >> 4;
    int r0 = wave * 16;
    short8v a[4], b[3][4];
    #pragma unroll
    for (int kf = 0; kf < 4; ++kf)
        a[kf] = *(const short8v*)&ha[r0 + fr][kf * 32 + fq * 8];
    #pragma unroll
    for (int n = 0; n < 3; ++n)
        #pragma unroll
        for (int kf = 0; kf < 4; ++kf)
            b[n][kf] = *(const short8v*)&wt[n * 16 + fr][kf * 32 + fq * 8];
    f32x4 acc[3] = {};
    #pragma unroll
    for (int n = 0; n < 3; ++n)
        #pragma unroll
        for (int kf = 0; kf < 4; ++kf)
            acc[n] = __builtin_amdgcn_mfma_f32_16x16x32_bf16(a[kf], b[n][kf], acc[n], 0, 0, 0);
    #pragma unroll
    for (int n = 0; n < 3; ++n) {
        #pragma unroll
        for (int j = 0; j < 4; ++j) {
            int gr = node0 + r0 + fq * 4 + j;
            int col = n * 16 + fr;
            if (gr < N_NODES && col < H2P)
                h2b[(size_t)gr * H2P + col] = (col < NCLASS) ? f2bf(acc[n][j]) : 0;
        }
    }
}

// ---------------- Aggregation 2 + bias + log_softmax -> out ----------------
// one WAVE per node; lanes 0-23 / 32-55 each load 4B (2 feats of 48-col row);
// 2 edges per instruction; softmax reduce within each 32-lane half.

__global__ __launch_bounds__(256) void agg2_kernel(const ushort* __restrict__ h2b,
                                                   const int* __restrict__ row_start,
                                                   const int* __restrict__ counts,
                                                   const int2* __restrict__ csr,
                                                   const float* __restrict__ dinv,
                                                   const float* __restrict__ b2,
                                                   float* __restrict__ out, int n) {
    int wv = threadIdx.x >> 6;
    int i = blockIdx.x * 4 + wv;
    if (i >= n) return;
    int l = threadIdx.x & 63;
    int h = l >> 5, q = l & 31;
    bool act = q < 24;
    int qq = act ? q : 0;
    const ushort* rowp = h2b + 2 * qq;   // this lane's 2-feature slice

    float di = dinv[i];
    float sc = (h == 0 && act) ? di * di : 0.f;
    unsigned sv = *(const unsigned*)(rowp + (size_t)i * H2P);
    float2 acc;
    acc.x = sc * blo(sv); acc.y = sc * bhi(sv);

    int lo = row_start[i], hi = lo + ((counts[i] + 7) & ~7);
    for (int e = lo; e < hi; e += 8) {
        int2 pA = csr[e + 0 + h];
        int2 pB = csr[e + 2 + h];
        int2 pC = csr[e + 4 + h];
        int2 pD = csr[e + 6 + h];
        unsigned vA = *(const unsigned*)(rowp + (size_t)pA.x * H2P);
        unsigned vB = *(const unsigned*)(rowp + (size_t)pB.x * H2P);
        unsigned vC = *(const unsigned*)(rowp + (size_t)pC.x * H2P);
        unsigned vD = *(const unsigned*)(rowp + (size_t)pD.x * H2P);
        float wA = __int_as_float(pA.y), wB = __int_as_float(pB.y);
        float wC = __int_as_float(pC.y), wD = __int_as_float(pD.y);
        acc.x = fmaf(wA, blo(vA), acc.x); acc.y = fmaf(wA, bhi(vA), acc.y);
        acc.x = fmaf(wB, blo(vB), acc.x); acc.y = fmaf(wB, bhi(vB), acc.y);
        acc.x = fmaf(wC, blo(vC), acc.x); acc.y = fmaf(wC, bhi(vC), acc.y);
        acc.x = fmaf(wD, blo(vD), acc.x); acc.y = fmaf(wD, bhi(vD), acc.y);
    }
    acc.x += __shfl_xor(acc.x, 32);
    acc.y += __shfl_xor(acc.y, 32);

    // log-softmax over 47 classes held 2-per-lane in lanes 0-23 of each half
    float v0 = -1e30f, v1 = -1e30f;
    if (act) {
        v0 = acc.x + b2[2 * q];
        v1 = (2 * q + 1 < NCLASS) ? (acc.y + b2[2 * q + 1]) : -1e30f;
    }
    float pm = fmaxf(v0, v1);
    #pragma unroll
    for (int off = 16; off; off >>= 1) pm = fmaxf(pm, __shfl_xor(pm, off));
    float ex = 0.f;
    if (act) {
        ex = __expf(v0 - pm);
        if (2 * q + 1 < NCLASS) ex += __expf(v1 - pm);
    }
    #pragma unroll
    for (int off = 16; off; off >>= 1) ex += __shfl_xor(ex, off);
    if (h == 0 && act) {
        float ls = pm + __logf(ex);
        out[(size_t)i * NCLASS + 2 * q] = v0 - ls;
        if (2 * q + 1 < NCLASS) out[(size_t)i * NCLASS + 2 * q + 1] = v1 - ls;
    }
}

// ---------------- launch ----------------

extern "C" void kernel_launch(void* const* d_in, const int* in_sizes, int n_in,
                              void* d_out, int out_size, void* d_ws, size_t ws_size,
                              hipStream_t stream) {
    const float* x  = (const float*)d_in[0];
    const int*   ei = (const int*)d_in[1];
    const float* ew = (const float*)d_in[2];
    const float* W1 = (const float*)d_in[3];
    const float* b1 = (const float*)d_in[4];
    const float* W2 = (const float*)d_in[5];
    const float* b2 = (const float*)d_in[6];
    float* out = (float*)d_out;

    const int* e_src = ei;
    const int* e_dst = ei + N_EDGES;

    char* p = (char*)d_ws;
    auto carve = [&](size_t bytes) { void* r = (void*)p; p += (bytes + 255) & ~(size_t)255; return r; };
    unsigned long long* packed = (unsigned long long*)carve(N_NODES * 8);
    float*  dinv      = (float*) carve(N_NODES * 4);
    int*    counts    = (int*)   carve(N_NODES * 4);
    int*    row_start = (int*)   carve(N_NODES * 4);
    int*    total     = (int*)   carve(4);
    int*    pos       = (int*)   carve((size_t)N_EDGES * 4);
    int2*   csr       = (int2*)  carve((size_t)CSR_MAX * 8);
    ushort* h1b       = (ushort*)carve((size_t)N_NODES * NHID * 2);
    ushort* haggb     = (ushort*)carve((size_t)N_NODES * NHID * 2);
    ushort* h2b       = (ushort*)carve((size_t)N_NODES * H2P * 2);

    zero_init_kernel<<<(CSR_MAX + 255) / 256, 256, 0, stream>>>(packed, csr, total);
    degcnt_kernel<<<(N_EDGES + 255) / 256, 256, 0, stream>>>(e_dst, ew, packed, pos, N_EDGES);
    segalloc_kernel<<<(N_NODES + 255) / 256, 256, 0, stream>>>(packed, counts, dinv,
                                                               row_start, total, N_NODES);
    scatter_kernel<<<(N_EDGES + 255) / 256, 256, 0, stream>>>(e_src, e_dst, ew, pos, dinv,
                                                              row_start, csr, N_EDGES);
    gemm1_kernel<<<(N_NODES + 63) / 64, 256, 0, stream>>>(x, W1, h1b);
    agg1_kernel<<<(N_NODES + 3) / 4, 256, 0, stream>>>(h1b, row_start, counts, csr, dinv, b1, haggb);
    gemm2_kernel<<<(N_NODES + 63) / 64, 256, 0, stream>>>(haggb, W2, h2b);
    agg2_kernel<<<(N_NODES + 3) / 4, 256, 0, stream>>>(h2b, row_start, counts, csr, dinv, b2, out, N_NODES);
}

// Round 7
// 162.449 us; speedup vs baseline: 2.9855x; 1.1459x over previous
//
#include <hip/hip_runtime.h>

#define N_NODES 50000
#define N_EDGES 800000
#define NFEAT   256
#define NHID    128
#define NCLASS  47
#define H2P     48    // padded h2 row (bf16)
#define CSR_MAX (N_EDGES + 7 * N_NODES)   // every segment padded to multiple of 8

typedef __attribute__((ext_vector_type(8))) short short8v;
typedef __attribute__((ext_vector_type(4))) float f32x4;

__device__ __forceinline__ ushort f2bf(float f) {
    unsigned u = __float_as_uint(f);
    unsigned r = (u + 0x7FFF + ((u >> 16) & 1)) >> 16;   // round-to-nearest-even
    return (ushort)r;
}
__device__ __forceinline__ float bf2f(ushort b) {
    return __uint_as_float(((unsigned)b) << 16);
}
__device__ __forceinline__ float blo(unsigned u) { return __uint_as_float(u << 16); }
__device__ __forceinline__ float bhi(unsigned u) { return __uint_as_float(u & 0xFFFF0000u); }

// ---------------- weight prep: transpose+convert W1, W2 to bf16 once ----------------
// w1t[c][k] (128x256), w2t[c][k] (48x128, col 47 zeroed)

__global__ void wprep_kernel(const float* __restrict__ W1, const float* __restrict__ W2,
                             ushort* __restrict__ w1t, ushort* __restrict__ w2t) {
    int t = blockIdx.x * blockDim.x + threadIdx.x;
    if (t < NFEAT * NHID) {              // read coalesced over c-fast
        int k = t >> 7, c = t & 127;
        w1t[c * NFEAT + k] = f2bf(W1[(size_t)k * NHID + c]);
    }
    if (t < NHID * H2P) {
        int k = t / H2P, c = t % H2P;
        w2t[c * NHID + k] = (c < NCLASS) ? f2bf(W2[(size_t)k * NCLASS + c]) : 0;
    }
}

// ---------------- CSR build ----------------
// packed[d]: high 24 bits = edge count, low 40 bits = sum(w) in 2^-20 fixed point.
// One 64-bit atomic per edge; the returned old count doubles as the CSR slot index.

__global__ void zero_init_kernel(unsigned long long* __restrict__ packed,
                                 int2* __restrict__ csr, int* __restrict__ total) {
    int i = blockIdx.x * blockDim.x + threadIdx.x;
    if (i < CSR_MAX) csr[i] = make_int2(0, 0);   // src=0, w=+0.0f (pad entries)
    if (i < N_NODES) packed[i] = 0ull;
    if (i == 0) *total = 0;
}

__global__ void degcnt_kernel(const int* __restrict__ dst, const float* __restrict__ w,
                              unsigned long long* __restrict__ packed,
                              int* __restrict__ pos, int E) {
    int e = blockIdx.x * blockDim.x + threadIdx.x;
    if (e >= E) return;
    int d = dst[e];
    unsigned fx = __float2uint_rn(w[e] * 1048576.0f);
    unsigned long long old = atomicAdd(&packed[d], (1ull << 40) | (unsigned long long)fx);
    pos[e] = (int)(old >> 40);
}

// segment allocator + dinv: block-local scan + one atomicAdd per block for the base.
__global__ __launch_bounds__(256) void segalloc_kernel(const unsigned long long* __restrict__ packed,
                                                       int* __restrict__ counts,
                                                       float* __restrict__ dinv,
                                                       int* __restrict__ row_start,
                                                       int* __restrict__ total, int n) {
    __shared__ int s[256];
    __shared__ int base_s;
    int t = threadIdx.x;
    int i = blockIdx.x * 256 + t;
    int v = 0;
    if (i < n) {
        unsigned long long pk = packed[i];
        int cnt = (int)(pk >> 40);
        counts[i] = cnt;
        float deg = 1.0f + (float)(pk & 0xFFFFFFFFFFull) * (1.0f / 1048576.0f);
        dinv[i] = rsqrtf(deg);
        v = (cnt + 7) & ~7;
    }
    s[t] = v;
    __syncthreads();
    #pragma unroll
    for (int off = 1; off < 256; off <<= 1) {
        int x = s[t];
        if (t >= off) x += s[t - off];
        __syncthreads();
        s[t] = x;
        __syncthreads();
    }
    if (t == 255) base_s = atomicAdd(total, s[255]);
    __syncthreads();
    if (i < n) row_start[i] = base_s + s[t] - v;
}

// atomic-free scatter: slot index was allocated by degcnt's returned count
__global__ void scatter_kernel(const int* __restrict__ src, const int* __restrict__ dst,
                               const float* __restrict__ w, const int* __restrict__ pos,
                               const float* __restrict__ dinv,
                               const int* __restrict__ row_start,
                               int2* __restrict__ csr, int E) {
    int e = blockIdx.x * blockDim.x + threadIdx.x;
    if (e >= E) return;
    int d = dst[e], s = src[e];
    int p = row_start[d] + pos[e];
    int2 pr;
    pr.x = s;
    pr.y = __float_as_int(dinv[s] * w[e] * dinv[d]);
    csr[p] = pr;
}

// ---------------- Layer 1 GEMM (MFMA bf16): h1b = bf16(x @ W1) ----------------
// B-tile now staged from pre-transposed bf16 w1t with linear coalesced b128 copies.

__global__ __launch_bounds__(256) void gemm1_kernel(const float* __restrict__ x,
                                                    const ushort* __restrict__ w1t,
                                                    ushort* __restrict__ h1b) {
    __shared__ __align__(16) ushort xs[64][72];
    __shared__ __align__(16) ushort ws[128][72];
    int tid = threadIdx.x;
    int node0 = blockIdx.x * 64;
    int wave = tid >> 6, l = tid & 63;
    int fr = l & 15, fq = l >> 4;
    int r0 = (wave >> 1) * 32;
    int c0 = (wave & 1) * 64;

    f32x4 acc[2][4] = {};

    for (int kk0 = 0; kk0 < NFEAT; kk0 += 64) {
        // stage x tile (f32 -> bf16): coalesced float4 reads
        {
            int row = tid >> 2, q = tid & 3;
            int srow = node0 + row; if (srow >= N_NODES) srow = N_NODES - 1;
            const float4* src = (const float4*)(x + (size_t)srow * NFEAT + kk0 + q * 16);
            ushort tmp[16];
            #pragma unroll
            for (int i = 0; i < 4; ++i) {
                float4 v = src[i];
                tmp[i * 4 + 0] = f2bf(v.x); tmp[i * 4 + 1] = f2bf(v.y);
                tmp[i * 4 + 2] = f2bf(v.z); tmp[i * 4 + 3] = f2bf(v.w);
            }
            #pragma unroll
            for (int i = 0; i < 2; ++i)
                *(short8v*)&xs[row][q * 16 + i * 8] = *(short8v*)&tmp[i * 8];
        }
        // stage w1t tile: pure linear copy (no transpose, no convert)
        {
            int rr = tid >> 3;       // 0..31
            int cq = tid & 7;        // 16B chunk in the 128B k-span
            #pragma unroll
            for (int i = 0; i < 4; ++i) {
                int row = rr + i * 32;
                *(short8v*)&ws[row][cq * 8] =
                    *(const short8v*)&w1t[(size_t)row * NFEAT + kk0 + cq * 8];
            }
        }
        __syncthreads();
        short8v a[2][2], b[4][2];
        #pragma unroll
        for (int m = 0; m < 2; ++m)
            #pragma unroll
            for (int kf = 0; kf < 2; ++kf)
                a[m][kf] = *(const short8v*)&xs[r0 + m * 16 + fr][kf * 32 + fq * 8];
        #pragma unroll
        for (int n = 0; n < 4; ++n)
            #pragma unroll
            for (int kf = 0; kf < 2; ++kf)
                b[n][kf] = *(const short8v*)&ws[c0 + n * 16 + fr][kf * 32 + fq * 8];
        #pragma unroll
        for (int m = 0; m < 2; ++m)
            #pragma unroll
            for (int n = 0; n < 4; ++n)
                #pragma unroll
                for (int kf = 0; kf < 2; ++kf)
                    acc[m][n] = __builtin_amdgcn_mfma_f32_16x16x32_bf16(
                        a[m][kf], b[n][kf], acc[m][n], 0, 0, 0);
        __syncthreads();
    }
    #pragma unroll
    for (int m = 0; m < 2; ++m) {
        #pragma unroll
        for (int n = 0; n < 4; ++n) {
            #pragma unroll
            for (int j = 0; j < 4; ++j) {
                int gr = node0 + r0 + m * 16 + fq * 4 + j;
                if (gr < N_NODES)
                    h1b[(size_t)gr * NHID + c0 + n * 16 + fr] = f2bf(acc[m][n][j]);
            }
        }
    }
}

// ---------------- Aggregation 1: haggb = bf16(relu(A_norm @ h1 + b1)) ----------------
// one WAVE per node; lane = (half h, quarter q). Each lane gathers 8B (4 feats);
// the two 32-lane halves process 2 edges per instruction; 8 edges per iteration.

__global__ __launch_bounds__(256) void agg1_kernel(const ushort* __restrict__ h1b,
                                                   const int* __restrict__ row_start,
                                                   const int* __restrict__ counts,
                                                   const int2* __restrict__ csr,
                                                   const float* __restrict__ dinv,
                                                   const float* __restrict__ b1,
                                                   ushort* __restrict__ haggb) {
    int wv = threadIdx.x >> 6;
    int i = blockIdx.x * 4 + wv;
    int l = threadIdx.x & 63;
    int h = l >> 5, q = l & 31;
    const ushort* rowp = h1b + 4 * q;    // this lane's 4-feature slice

    float di = dinv[i];
    float sc = (h == 0) ? di * di : 0.f;
    uint2 sv = *(const uint2*)(rowp + (size_t)i * NHID);
    float4 acc;
    acc.x = sc * blo(sv.x); acc.y = sc * bhi(sv.x);
    acc.z = sc * blo(sv.y); acc.w = sc * bhi(sv.y);

    int lo = row_start[i], hi = lo + ((counts[i] + 7) & ~7);
    for (int e = lo; e < hi; e += 8) {
        int2 pA = csr[e + 0 + h];
        int2 pB = csr[e + 2 + h];
        int2 pC = csr[e + 4 + h];
        int2 pD = csr[e + 6 + h];
        uint2 vA = *(const uint2*)(rowp + (size_t)pA.x * NHID);
        uint2 vB = *(const uint2*)(rowp + (size_t)pB.x * NHID);
        uint2 vC = *(const uint2*)(rowp + (size_t)pC.x * NHID);
        uint2 vD = *(const uint2*)(rowp + (size_t)pD.x * NHID);
        float wA = __int_as_float(pA.y), wB = __int_as_float(pB.y);
        float wC = __int_as_float(pC.y), wD = __int_as_float(pD.y);
        acc.x = fmaf(wA, blo(vA.x), acc.x); acc.y = fmaf(wA, bhi(vA.x), acc.y);
        acc.z = fmaf(wA, blo(vA.y), acc.z); acc.w = fmaf(wA, bhi(vA.y), acc.w);
        acc.x = fmaf(wB, blo(vB.x), acc.x); acc.y = fmaf(wB, bhi(vB.x), acc.y);
        acc.z = fmaf(wB, blo(vB.y), acc.z); acc.w = fmaf(wB, bhi(vB.y), acc.w);
        acc.x = fmaf(wC, blo(vC.x), acc.x); acc.y = fmaf(wC, bhi(vC.x), acc.y);
        acc.z = fmaf(wC, blo(vC.y), acc.z); acc.w = fmaf(wC, bhi(vC.y), acc.w);
        acc.x = fmaf(wD, blo(vD.x), acc.x); acc.y = fmaf(wD, bhi(vD.x), acc.y);
        acc.z = fmaf(wD, blo(vD.y), acc.z); acc.w = fmaf(wD, bhi(vD.y), acc.w);
    }
    // combine the two halves
    acc.x += __shfl_xor(acc.x, 32);
    acc.y += __shfl_xor(acc.y, 32);
    acc.z += __shfl_xor(acc.z, 32);
    acc.w += __shfl_xor(acc.w, 32);
    if (h == 0) {
        float4 bb = *(const float4*)(b1 + 4 * q);
        acc.x = fmaxf(acc.x + bb.x, 0.f);
        acc.y = fmaxf(acc.y + bb.y, 0.f);
        acc.z = fmaxf(acc.z + bb.z, 0.f);
        acc.w = fmaxf(acc.w + bb.w, 0.f);
        uint2 o;
        o.x = (unsigned)f2bf(acc.x) | ((unsigned)f2bf(acc.y) << 16);
        o.y = (unsigned)f2bf(acc.z) | ((unsigned)f2bf(acc.w) << 16);
        *(uint2*)(haggb + (size_t)i * NHID + 4 * q) = o;
    }
}

// ---------------- Layer 2 GEMM (MFMA bf16): h2b = bf16(hagg @ W2), rows padded to 48 ----------------

__global__ __launch_bounds__(256) void gemm2_kernel(const ushort* __restrict__ haggb,
                                                    const ushort* __restrict__ w2t,
                                                    ushort* __restrict__ h2b) {
    __shared__ __align__(16) ushort ha[64][136];
    __shared__ __align__(16) ushort wt[48][136];
    int tid = threadIdx.x;
    int node0 = blockIdx.x * 64;
    {
        int row = tid >> 2, q = tid & 3;
        int srow = node0 + row; if (srow >= N_NODES) srow = N_NODES - 1;
        const short8v* src = (const short8v*)(haggb + (size_t)srow * NHID + q * 32);
        #pragma unroll
        for (int i = 0; i < 4; ++i)
            *(short8v*)&ha[row][q * 32 + i * 8] = src[i];
    }
    {   // stage w2t: pure linear copy, 768 x 16B chunks
        #pragma unroll
        for (int i = 0; i < 3; ++i) {
            int id = tid + i * 256;
            int row = id >> 4, cq = id & 15;
            *(short8v*)&wt[row][cq * 8] =
                *(const short8v*)&w2t[(size_t)row * NHID + cq * 8];
        }
    }
    __syncthreads();
    int wave = tid >> 6, l = tid & 63;
    int fr = l & 15, fq = l >> 4;
    int r0 = wave * 16;
    short8v a[4], b[3][4];
    #pragma unroll
    for (int kf = 0; kf < 4; ++kf)
        a[kf] = *(const short8v*)&ha[r0 + fr][kf * 32 + fq * 8];
    #pragma unroll
    for (int n = 0; n < 3; ++n)
        #pragma unroll
        for (int kf = 0; kf < 4; ++kf)
            b[n][kf] = *(const short8v*)&wt[n * 16 + fr][kf * 32 + fq * 8];
    f32x4 acc[3] = {};
    #pragma unroll
    for (int n = 0; n < 3; ++n)
        #pragma unroll
        for (int kf = 0; kf < 4; ++kf)
            acc[n] = __builtin_amdgcn_mfma_f32_16x16x32_bf16(a[kf], b[n][kf], acc[n], 0, 0, 0);
    #pragma unroll
    for (int n = 0; n < 3; ++n) {
        #pragma unroll
        for (int j = 0; j < 4; ++j) {
            int gr = node0 + r0 + fq * 4 + j;
            int col = n * 16 + fr;
            if (gr < N_NODES && col < H2P)
                h2b[(size_t)gr * H2P + col] = (col < NCLASS) ? f2bf(acc[n][j]) : 0;
        }
    }
}

// ---------------- Aggregation 2 + bias + log_softmax -> out ----------------
// one WAVE per node; lanes 0-23 / 32-55 each load 4B (2 feats of 48-col row);
// 2 edges per instruction; softmax reduce within each 32-lane half.

__global__ __launch_bounds__(256) void agg2_kernel(const ushort* __restrict__ h2b,
                                                   const int* __restrict__ row_start,
                                                   const int* __restrict__ counts,
                                                   const int2* __restrict__ csr,
                                                   const float* __restrict__ dinv,
                                                   const float* __restrict__ b2,
                                                   float* __restrict__ out, int n) {
    int wv = threadIdx.x >> 6;
    int i = blockIdx.x * 4 + wv;
    if (i >= n) return;
    int l = threadIdx.x & 63;
    int h = l >> 5, q = l & 31;
    bool act = q < 24;
    int qq = act ? q : 0;
    const ushort* rowp = h2b + 2 * qq;   // this lane's 2-feature slice

    float di = dinv[i];
    float sc = (h == 0 && act) ? di * di : 0.f;
    unsigned sv = *(const unsigned*)(rowp + (size_t)i * H2P);
    float2 acc;
    acc.x = sc * blo(sv); acc.y = sc * bhi(sv);

    int lo = row_start[i], hi = lo + ((counts[i] + 7) & ~7);
    for (int e = lo; e < hi; e += 8) {
        int2 pA = csr[e + 0 + h];
        int2 pB = csr[e + 2 + h];
        int2 pC = csr[e + 4 + h];
        int2 pD = csr[e + 6 + h];
        unsigned vA = *(const unsigned*)(rowp + (size_t)pA.x * H2P);
        unsigned vB = *(const unsigned*)(rowp + (size_t)pB.x * H2P);
        unsigned vC = *(const unsigned*)(rowp + (size_t)pC.x * H2P);
        unsigned vD = *(const unsigned*)(rowp + (size_t)pD.x * H2P);
        float wA = __int_as_float(pA.y), wB = __int_as_float(pB.y);
        float wC = __int_as_float(pC.y), wD = __int_as_float(pD.y);
        acc.x = fmaf(wA, blo(vA), acc.x); acc.y = fmaf(wA, bhi(vA), acc.y);
        acc.x = fmaf(wB, blo(vB), acc.x); acc.y = fmaf(wB, bhi(vB), acc.y);
        acc.x = fmaf(wC, blo(vC), acc.x); acc.y = fmaf(wC, bhi(vC), acc.y);
        acc.x = fmaf(wD, blo(vD), acc.x); acc.y = fmaf(wD, bhi(vD), acc.y);
    }
    acc.x += __shfl_xor(acc.x, 32);
    acc.y += __shfl_xor(acc.y, 32);

    // log-softmax over 47 classes held 2-per-lane in lanes 0-23 of each half
    float v0 = -1e30f, v1 = -1e30f;
    if (act) {
        v0 = acc.x + b2[2 * q];
        v1 = (2 * q + 1 < NCLASS) ? (acc.y + b2[2 * q + 1]) : -1e30f;
    }
    float pm = fmaxf(v0, v1);
    #pragma unroll
    for (int off = 16; off; off >>= 1) pm = fmaxf(pm, __shfl_xor(pm, off));
    float ex = 0.f;
    if (act) {
        ex = __expf(v0 - pm);
        if (2 * q + 1 < NCLASS) ex += __expf(v1 - pm);
    }
    #pragma unroll
    for (int off = 16; off; off >>= 1) ex += __shfl_xor(ex, off);
    if (h == 0 && act) {
        float ls = pm + __logf(ex);
        out[(size_t)i * NCLASS + 2 * q] = v0 - ls;
        if (2 * q + 1 < NCLASS) out[(size_t)i * NCLASS + 2 * q + 1] = v1 - ls;
    }
}

// ---------------- launch ----------------

extern "C" void kernel_launch(void* const* d_in, const int* in_sizes, int n_in,
                              void* d_out, int out_size, void* d_ws, size_t ws_size,
                              hipStream_t stream) {
    const float* x  = (const float*)d_in[0];
    const int*   ei = (const int*)d_in[1];
    const float* ew = (const float*)d_in[2];
    const float* W1 = (const float*)d_in[3];
    const float* b1 = (const float*)d_in[4];
    const float* W2 = (const float*)d_in[5];
    const float* b2 = (const float*)d_in[6];
    float* out = (float*)d_out;

    const int* e_src = ei;
    const int* e_dst = ei + N_EDGES;

    char* p = (char*)d_ws;
    auto carve = [&](size_t bytes) { void* r = (void*)p; p += (bytes + 255) & ~(size_t)255; return r; };
    unsigned long long* packed = (unsigned long long*)carve(N_NODES * 8);
    float*  dinv      = (float*) carve(N_NODES * 4);
    int*    counts    = (int*)   carve(N_NODES * 4);
    int*    row_start = (int*)   carve(N_NODES * 4);
    int*    total     = (int*)   carve(4);
    int*    pos       = (int*)   carve((size_t)N_EDGES * 4);
    int2*   csr       = (int2*)  carve((size_t)CSR_MAX * 8);
    ushort* h1b       = (ushort*)carve((size_t)N_NODES * NHID * 2);
    ushort* haggb     = (ushort*)carve((size_t)N_NODES * NHID * 2);
    ushort* h2b       = (ushort*)carve((size_t)N_NODES * H2P * 2);
    ushort* w1t       = (ushort*)carve((size_t)NHID * NFEAT * 2);
    ushort* w2t       = (ushort*)carve((size_t)H2P * NHID * 2);

    wprep_kernel<<<(NFEAT * NHID + 255) / 256, 256, 0, stream>>>(W1, W2, w1t, w2t);
    zero_init_kernel<<<(CSR_MAX + 255) / 256, 256, 0, stream>>>(packed, csr, total);
    degcnt_kernel<<<(N_EDGES + 255) / 256, 256, 0, stream>>>(e_dst, ew, packed, pos, N_EDGES);
    segalloc_kernel<<<(N_NODES + 255) / 256, 256, 0, stream>>>(packed, counts, dinv,
                                                               row_start, total, N_NODES);
    scatter_kernel<<<(N_EDGES + 255) / 256, 256, 0, stream>>>(e_src, e_dst, ew, pos, dinv,
                                                              row_start, csr, N_EDGES);
    gemm1_kernel<<<(N_NODES + 63) / 64, 256, 0, stream>>>(x, w1t, h1b);
    agg1_kernel<<<(N_NODES + 3) / 4, 256, 0, stream>>>(h1b, row_start, counts, csr, dinv, b1, haggb);
    gemm2_kernel<<<(N_NODES + 63) / 64, 256, 0, stream>>>(haggb, w2t, h2b);
    agg2_kernel<<<(N_NODES + 3) / 4, 256, 0, stream>>>(h2b, row_start, counts, csr, dinv, b2, out, N_NODES);
}